// Round 1
// baseline (2117.851 us; speedup 1.0000x reference)
//
#include <hip/hip_runtime.h>
#include <math.h>

#define Bsz 1024
#define Tt  128
#define Ff  32
#define Ee  16
#define Hh  20
#define Dd  4096
#define EPSc 1e-3f

__device__ __forceinline__ float sigmoidf_(float x) {
    return 1.0f / (1.0f + __expf(-x));
}

// ---------------------------------------------------------------- BN (inference)
__global__ void bn_kernel(const float* __restrict__ x,
                          const float* __restrict__ gamma, const float* __restrict__ beta,
                          const float* __restrict__ mean,  const float* __restrict__ var,
                          float* __restrict__ xn, int n4)
{
    __shared__ float sc[Ff], sh[Ff];
    int tid = threadIdx.x;
    if (tid < Ff) {
        float s = gamma[tid] * rsqrtf(var[tid] + EPSc);
        sc[tid] = s;
        sh[tid] = beta[tid] - mean[tid] * s;
    }
    __syncthreads();
    const float4* x4 = (const float4*)x;
    float4* o4 = (float4*)xn;
    for (int i = blockIdx.x * blockDim.x + tid; i < n4; i += gridDim.x * blockDim.x) {
        float4 v = x4[i];
        int f0 = (i & 7) * 4;
        v.x = v.x * sc[f0 + 0] + sh[f0 + 0];
        v.y = v.y * sc[f0 + 1] + sh[f0 + 1];
        v.z = v.z * sc[f0 + 2] + sh[f0 + 2];
        v.w = v.w * sc[f0 + 3] + sh[f0 + 3];
        o4[i] = v;
    }
}

// ---------------------------------------------------------------- fc1: relu(A@W + b), fp32 SGEMM
// A=[1024][4096] (raw x flat), W=[4096][4096], C=[1024][4096]
#define BM 128
#define BN 128
#define BKk 16
__global__ __launch_bounds__(256) void fc1_gemm(const float* __restrict__ A,
                                                const float* __restrict__ W,
                                                const float* __restrict__ bias,
                                                float* __restrict__ C)
{
    __shared__ float As[BKk][BM];
    __shared__ float Ws[BKk][BN];
    int tid = threadIdx.x;
    int m0 = blockIdx.y * BM;
    int n0 = blockIdx.x * BN;
    int tx = tid & 15, ty = tid >> 4;

    int am[2], ak[2], wk[2], wn[2];
#pragma unroll
    for (int q = 0; q < 2; ++q) {
        int id = tid + q * 256;
        am[q] = id >> 2;        // 0..127
        ak[q] = (id & 3) * 4;   // 0..12
        wk[q] = id >> 5;        // 0..15
        wn[q] = (id & 31) * 4;  // 0..124
    }

    float acc[8][8];
#pragma unroll
    for (int i = 0; i < 8; ++i)
#pragma unroll
        for (int j = 0; j < 8; ++j) acc[i][j] = 0.f;

    float4 aReg[2], wReg[2];
#pragma unroll
    for (int q = 0; q < 2; ++q) {
        aReg[q] = *(const float4*)&A[(size_t)(m0 + am[q]) * Dd + 0 + ak[q]];
        wReg[q] = *(const float4*)&W[(size_t)(0 + wk[q]) * Dd + n0 + wn[q]];
    }

    for (int k0 = 0; k0 < Dd; k0 += BKk) {
        __syncthreads();
#pragma unroll
        for (int q = 0; q < 2; ++q) {
            As[ak[q] + 0][am[q]] = aReg[q].x;
            As[ak[q] + 1][am[q]] = aReg[q].y;
            As[ak[q] + 2][am[q]] = aReg[q].z;
            As[ak[q] + 3][am[q]] = aReg[q].w;
            *(float4*)&Ws[wk[q]][wn[q]] = wReg[q];
        }
        __syncthreads();
        int kn = k0 + BKk;
        if (kn < Dd) {
#pragma unroll
            for (int q = 0; q < 2; ++q) {
                aReg[q] = *(const float4*)&A[(size_t)(m0 + am[q]) * Dd + kn + ak[q]];
                wReg[q] = *(const float4*)&W[(size_t)(kn + wk[q]) * Dd + n0 + wn[q]];
            }
        }
#pragma unroll
        for (int k = 0; k < BKk; ++k) {
            float a[8], b[8];
            *(float4*)&a[0] = *(float4*)&As[k][ty * 8];
            *(float4*)&a[4] = *(float4*)&As[k][ty * 8 + 4];
            *(float4*)&b[0] = *(float4*)&Ws[k][tx * 8];
            *(float4*)&b[4] = *(float4*)&Ws[k][tx * 8 + 4];
#pragma unroll
            for (int i = 0; i < 8; ++i)
#pragma unroll
                for (int j = 0; j < 8; ++j) acc[i][j] += a[i] * b[j];
        }
    }

    float bv[8];
#pragma unroll
    for (int j = 0; j < 8; ++j) bv[j] = bias[n0 + tx * 8 + j];
#pragma unroll
    for (int i = 0; i < 8; ++i) {
        int m = m0 + ty * 8 + i;
        float4 v0, v1;
        v0.x = fmaxf(acc[i][0] + bv[0], 0.f);
        v0.y = fmaxf(acc[i][1] + bv[1], 0.f);
        v0.z = fmaxf(acc[i][2] + bv[2], 0.f);
        v0.w = fmaxf(acc[i][3] + bv[3], 0.f);
        v1.x = fmaxf(acc[i][4] + bv[4], 0.f);
        v1.y = fmaxf(acc[i][5] + bv[5], 0.f);
        v1.z = fmaxf(acc[i][6] + bv[6], 0.f);
        v1.w = fmaxf(acc[i][7] + bv[7], 0.f);
        *(float4*)&C[(size_t)m * Dd + n0 + tx * 8]     = v0;
        *(float4*)&C[(size_t)m * Dd + n0 + tx * 8 + 4] = v1;
    }
}

// ---------------------------------------------------------------- gate: softmax(g @ gate_w + gb)
__global__ __launch_bounds__(256) void gate_kernel(const float* __restrict__ g,
                                                   const float* __restrict__ gw,
                                                   const float* __restrict__ gb,
                                                   float* __restrict__ wgt)
{
    int b = blockIdx.x;
    int tid = threadIdx.x;
    int lane = tid & 63;
    int wv = tid >> 6;

    float acc[16];
#pragma unroll
    for (int j = 0; j < 16; ++j) acc[j] = 0.f;

    const float* grow = g + (size_t)b * Dd;
#pragma unroll
    for (int it = 0; it < Dd / 256; ++it) {
        int d = tid + it * 256;
        float gv = grow[d];
        const float4* wr = (const float4*)(gw + (size_t)d * 16);
        float4 w0 = wr[0], w1 = wr[1], w2 = wr[2], w3 = wr[3];
        acc[0] += gv * w0.x;  acc[1] += gv * w0.y;  acc[2] += gv * w0.z;  acc[3] += gv * w0.w;
        acc[4] += gv * w1.x;  acc[5] += gv * w1.y;  acc[6] += gv * w1.z;  acc[7] += gv * w1.w;
        acc[8] += gv * w2.x;  acc[9] += gv * w2.y;  acc[10] += gv * w2.z; acc[11] += gv * w2.w;
        acc[12] += gv * w3.x; acc[13] += gv * w3.y; acc[14] += gv * w3.z; acc[15] += gv * w3.w;
    }

    __shared__ float red[64];
    __shared__ float logits[16];
#pragma unroll
    for (int j = 0; j < 16; ++j) {
        float v = acc[j];
#pragma unroll
        for (int m = 32; m >= 1; m >>= 1) v += __shfl_xor(v, m);
        if (lane == 0) red[wv * 16 + j] = v;
    }
    __syncthreads();
    if (tid < 16) {
        logits[tid] = gb[tid] + red[tid] + red[16 + tid] + red[32 + tid] + red[48 + tid];
    }
    __syncthreads();
    if (tid == 0) {
        float m = logits[0];
#pragma unroll
        for (int j = 1; j < 16; ++j) m = fmaxf(m, logits[j]);
        float ex[16], s = 0.f;
#pragma unroll
        for (int j = 0; j < 16; ++j) { ex[j] = __expf(logits[j] - m); s += ex[j]; }
        float inv = 1.f / s;
#pragma unroll
        for (int j = 0; j < 16; ++j) wgt[(size_t)b * 16 + j] = ex[j] * inv;
    }
}

// ---------------------------------------------------------------- fused 2-layer LSTM scan per expert
// grid = 256 blocks: block = (expert e, batch chunk of 64). 256 thr = 4 waves.
// lane = batch row (within chunk); wave w owns hidden units [5w, 5w+5) of both LSTMs.
// Weight reads are wave-uniform -> scalar (s_load) path; h-state shared via double-buffered LDS.
__global__ __launch_bounds__(256, 1) void lstm_kernel(
    const float* __restrict__ xn,
    const float* __restrict__ k1, const float* __restrict__ r1, const float* __restrict__ b1,
    const float* __restrict__ k2, const float* __restrict__ r2, const float* __restrict__ b2,
    const float* __restrict__ dw, const float* __restrict__ db,
    float* __restrict__ eo)
{
    const int e   = blockIdx.x >> 4;
    const int b0  = (blockIdx.x & 15) * 64;
    const int tid = threadIdx.x;
    const int lane = tid & 63;
    const int wv  = __builtin_amdgcn_readfirstlane(tid >> 6);
    const int U   = wv * 5;

    __shared__ float xs[2][Ff][64];
    __shared__ float h1s[2][Hh][64];
    __shared__ float h2s[2][Hh][64];

    const float* k1e = k1 + (size_t)e * Ff * 80;
    const float* r1e = r1 + (size_t)e * Hh * 80;
    const float* b1e = b1 + (size_t)e * 80;
    const float* k2e = k2 + (size_t)e * Hh * 80;
    const float* r2e = r2 + (size_t)e * Hh * 80;
    const float* b2e = b2 + (size_t)e * 80;

    {   // zero-init parity-0 state
        float* h10 = &h1s[0][0][0];
        float* h20 = &h2s[0][0][0];
        for (int i = tid; i < Hh * 64; i += 256) { h10[i] = 0.f; h20[i] = 0.f; }
    }

    float c1r[5] = {0.f, 0.f, 0.f, 0.f, 0.f};
    float c2r[5] = {0.f, 0.f, 0.f, 0.f, 0.f};

#pragma unroll 1
    for (int t = 0; t < Tt; ++t) {
        const int p = t & 1;
        // stage x_t for the 64 rows (transposed in LDS: xs[f][row])
#pragma unroll
        for (int q = 0; q < 2; ++q) {
            int id = tid + q * 256;
            int r  = id >> 3;
            int c4 = (id & 7) * 4;
            float4 v = *(const float4*)&xn[((size_t)(b0 + r) * Tt + t) * Ff + c4];
            xs[p][c4 + 0][r] = v.x;
            xs[p][c4 + 1][r] = v.y;
            xs[p][c4 + 2][r] = v.z;
            xs[p][c4 + 3][r] = v.w;
        }
        __syncthreads();  // A: x_t staged; h(t-1) visible

        float xf[Ff];
#pragma unroll
        for (int f = 0; f < Ff; ++f) xf[f] = xs[p][f][lane];
        float h1v[Hh], h2v[Hh];
#pragma unroll
        for (int k = 0; k < Hh; ++k) { h1v[k] = h1s[p][k][lane]; h2v[k] = h2s[p][k][lane]; }

        float z1[4][5], z2[4][5];
#pragma unroll
        for (int gg = 0; gg < 4; ++gg)
#pragma unroll
            for (int u = 0; u < 5; ++u) {
                z1[gg][u] = b1e[gg * 20 + U + u];
                z2[gg][u] = b2e[gg * 20 + U + u];
            }

        // LSTM1 input projection (x @ k1)
#pragma unroll
        for (int f = 0; f < Ff; ++f) {
            float xv = xf[f];
            const float* wrow = k1e + f * 80 + U;
#pragma unroll
            for (int gg = 0; gg < 4; ++gg)
#pragma unroll
                for (int u = 0; u < 5; ++u) z1[gg][u] += xv * wrow[gg * 20 + u];
        }
        // LSTM1 recurrent + LSTM2 recurrent (both use t-1 state)
#pragma unroll
        for (int k = 0; k < Hh; ++k) {
            float hv  = h1v[k];
            float hv2 = h2v[k];
            const float* w1 = r1e + k * 80 + U;
            const float* w2 = r2e + k * 80 + U;
#pragma unroll
            for (int gg = 0; gg < 4; ++gg)
#pragma unroll
                for (int u = 0; u < 5; ++u) {
                    z1[gg][u] += hv  * w1[gg * 20 + u];
                    z2[gg][u] += hv2 * w2[gg * 20 + u];
                }
        }
        // LSTM1 elementwise -> h1(t)
#pragma unroll
        for (int u = 0; u < 5; ++u) {
            float iv = sigmoidf_(z1[0][u]);
            float fv = sigmoidf_(z1[1][u]);
            float gv = fmaxf(z1[2][u], 0.f);
            float ov = sigmoidf_(z1[3][u]);
            float c  = fv * c1r[u] + iv * gv;
            c1r[u] = c;
            h1s[1 - p][U + u][lane] = ov * fmaxf(c, 0.f);
        }
        __syncthreads();  // B: full h1(t) visible

        // LSTM2 input projection (h1(t) @ k2)
#pragma unroll
        for (int k = 0; k < Hh; ++k) {
            float hv = h1s[1 - p][k][lane];
            const float* w = k2e + k * 80 + U;
#pragma unroll
            for (int gg = 0; gg < 4; ++gg)
#pragma unroll
                for (int u = 0; u < 5; ++u) z2[gg][u] += hv * w[gg * 20 + u];
        }
        // LSTM2 elementwise -> h2(t)
#pragma unroll
        for (int u = 0; u < 5; ++u) {
            float iv = sigmoidf_(z2[0][u]);
            float fv = sigmoidf_(z2[1][u]);
            float gv = fmaxf(z2[2][u], 0.f);
            float ov = sigmoidf_(z2[3][u]);
            float c  = fv * c2r[u] + iv * gv;
            c2r[u] = c;
            h2s[1 - p][U + u][lane] = ov * fmaxf(c, 0.f);
        }
        // no sync here: next iteration's sync A orders h2 write->read and xs re-stage
    }
    __syncthreads();
    if (tid < 64) {  // final h2 is in parity 0 (T even)
        float s = db[e];
#pragma unroll
        for (int k = 0; k < Hh; ++k) s += h2s[0][k][lane] * dw[e * Hh + k];
        eo[(size_t)e * Bsz + b0 + lane] = s;
    }
}

// ---------------------------------------------------------------- combine
__global__ void combine_kernel(const float* __restrict__ wgt,
                               const float* __restrict__ eo,
                               float* __restrict__ out)
{
    int b = blockIdx.x * blockDim.x + threadIdx.x;
    if (b < Bsz) {
        float s = 0.f;
#pragma unroll
        for (int e = 0; e < Ee; ++e) s += wgt[(size_t)b * 16 + e] * eo[(size_t)e * Bsz + b];
        out[b] = s;
    }
}

// ----------------------------------------------------------------
extern "C" void kernel_launch(void* const* d_in, const int* in_sizes, int n_in,
                              void* d_out, int out_size, void* d_ws, size_t ws_size,
                              hipStream_t stream)
{
    const float* x     = (const float*)d_in[0];
    const float* gamma = (const float*)d_in[1];
    const float* beta  = (const float*)d_in[2];
    const float* mean  = (const float*)d_in[3];
    const float* var   = (const float*)d_in[4];
    const float* k1    = (const float*)d_in[5];
    const float* r1    = (const float*)d_in[6];
    const float* b1    = (const float*)d_in[7];
    const float* k2    = (const float*)d_in[8];
    const float* r2    = (const float*)d_in[9];
    const float* b2    = (const float*)d_in[10];
    const float* dw    = (const float*)d_in[11];
    const float* db    = (const float*)d_in[12];
    const float* fc1w  = (const float*)d_in[13];
    const float* fc1b  = (const float*)d_in[14];
    const float* gw    = (const float*)d_in[15];
    const float* gb    = (const float*)d_in[16];
    float* out = (float*)d_out;

    float* xn  = (float*)d_ws;                    // 4,194,304 f
    float* g   = xn + (size_t)Bsz * Tt * Ff;      // 4,194,304 f
    float* wgt = g + (size_t)Bsz * Dd;            // 16,384 f
    float* eo  = wgt + (size_t)Bsz * Ee;          // 16,384 f

    bn_kernel<<<1024, 256, 0, stream>>>(x, gamma, beta, mean, var, xn, Bsz * Tt * Ff / 4);
    lstm_kernel<<<256, 256, 0, stream>>>(xn, k1, r1, b1, k2, r2, b2, dw, db, eo);
    fc1_gemm<<<dim3(Dd / BN, Bsz / BM), 256, 0, stream>>>(x, fc1w, fc1b, g);
    gate_kernel<<<Bsz, 256, 0, stream>>>(g, gw, gb, wgt);
    combine_kernel<<<4, 256, 0, stream>>>(wgt, eo, out);
}

// Round 2
// 2053.820 us; speedup vs baseline: 1.0312x; 1.0312x over previous
//
#include <hip/hip_runtime.h>
#include <math.h>

#define Bsz 1024
#define Tt  128
#define Ff  32
#define Ee  16
#define Hh  20
#define Dd  4096
#define EPSc 1e-3f

// packed-weight layout per (expert, wave): k1[32][20] @0, r1[20][20] @640,
// k2[20][20] @1040, r2[20][20] @1440, b1[20] @1840, b2[20] @1860 -> 1880 floats
#define PWSZ 1880

__device__ __forceinline__ float sigmoidf_(float x) {
    return 1.0f / (1.0f + __expf(-x));
}

// ---------------------------------------------------------------- BN (inference)
__global__ void bn_kernel(const float* __restrict__ x,
                          const float* __restrict__ gamma, const float* __restrict__ beta,
                          const float* __restrict__ mean,  const float* __restrict__ var,
                          float* __restrict__ xn, int n4)
{
    __shared__ float sc[Ff], sh[Ff];
    int tid = threadIdx.x;
    if (tid < Ff) {
        float s = gamma[tid] * rsqrtf(var[tid] + EPSc);
        sc[tid] = s;
        sh[tid] = beta[tid] - mean[tid] * s;
    }
    __syncthreads();
    const float4* x4 = (const float4*)x;
    float4* o4 = (float4*)xn;
    for (int i = blockIdx.x * blockDim.x + tid; i < n4; i += gridDim.x * blockDim.x) {
        float4 v = x4[i];
        int f0 = (i & 7) * 4;
        v.x = v.x * sc[f0 + 0] + sh[f0 + 0];
        v.y = v.y * sc[f0 + 1] + sh[f0 + 1];
        v.z = v.z * sc[f0 + 2] + sh[f0 + 2];
        v.w = v.w * sc[f0 + 3] + sh[f0 + 3];
        o4[i] = v;
    }
}

// ---------------------------------------------------------------- weight repack for lstm
__global__ void repack_kernel(const float* __restrict__ k1, const float* __restrict__ r1,
                              const float* __restrict__ b1, const float* __restrict__ k2,
                              const float* __restrict__ r2, const float* __restrict__ b2,
                              float* __restrict__ pw)
{
    int idx = blockIdx.x * blockDim.x + threadIdx.x;
    if (idx >= Ee * 4 * PWSZ) return;
    int ew = idx / PWSZ;
    int o  = idx % PWSZ;
    int e = ew >> 2, w = ew & 3;
    float v;
    if (o < 640) {
        int f = o / 20, c = o % 20, gg = c / 5, u = c % 5;
        v = k1[((size_t)e * Ff + f) * 80 + gg * 20 + w * 5 + u];
    } else if (o < 1040) {
        int k = (o - 640) / 20, c = (o - 640) % 20, gg = c / 5, u = c % 5;
        v = r1[((size_t)e * Hh + k) * 80 + gg * 20 + w * 5 + u];
    } else if (o < 1440) {
        int k = (o - 1040) / 20, c = (o - 1040) % 20, gg = c / 5, u = c % 5;
        v = k2[((size_t)e * Hh + k) * 80 + gg * 20 + w * 5 + u];
    } else if (o < 1840) {
        int k = (o - 1440) / 20, c = (o - 1440) % 20, gg = c / 5, u = c % 5;
        v = r2[((size_t)e * Hh + k) * 80 + gg * 20 + w * 5 + u];
    } else if (o < 1860) {
        int c = o - 1840, gg = c / 5, u = c % 5;
        v = b1[(size_t)e * 80 + gg * 20 + w * 5 + u];
    } else {
        int c = o - 1860, gg = c / 5, u = c % 5;
        v = b2[(size_t)e * 80 + gg * 20 + w * 5 + u];
    }
    pw[idx] = v;
}

// ---------------------------------------------------------------- fc1: relu(A@W + b), fp32 SGEMM
#define BM 128
#define BN 128
#define BKk 16
__global__ __launch_bounds__(256) void fc1_gemm(const float* __restrict__ A,
                                                const float* __restrict__ W,
                                                const float* __restrict__ bias,
                                                float* __restrict__ C)
{
    __shared__ float As[BKk][BM];
    __shared__ float Ws[BKk][BN];
    int tid = threadIdx.x;
    int m0 = blockIdx.y * BM;
    int n0 = blockIdx.x * BN;
    int tx = tid & 15, ty = tid >> 4;

    int am[2], ak[2], wk[2], wn[2];
#pragma unroll
    for (int q = 0; q < 2; ++q) {
        int id = tid + q * 256;
        am[q] = id >> 2;
        ak[q] = (id & 3) * 4;
        wk[q] = id >> 5;
        wn[q] = (id & 31) * 4;
    }

    float acc[8][8];
#pragma unroll
    for (int i = 0; i < 8; ++i)
#pragma unroll
        for (int j = 0; j < 8; ++j) acc[i][j] = 0.f;

    float4 aReg[2], wReg[2];
#pragma unroll
    for (int q = 0; q < 2; ++q) {
        aReg[q] = *(const float4*)&A[(size_t)(m0 + am[q]) * Dd + 0 + ak[q]];
        wReg[q] = *(const float4*)&W[(size_t)(0 + wk[q]) * Dd + n0 + wn[q]];
    }

    for (int k0 = 0; k0 < Dd; k0 += BKk) {
        __syncthreads();
#pragma unroll
        for (int q = 0; q < 2; ++q) {
            As[ak[q] + 0][am[q]] = aReg[q].x;
            As[ak[q] + 1][am[q]] = aReg[q].y;
            As[ak[q] + 2][am[q]] = aReg[q].z;
            As[ak[q] + 3][am[q]] = aReg[q].w;
            *(float4*)&Ws[wk[q]][wn[q]] = wReg[q];
        }
        __syncthreads();
        int kn = k0 + BKk;
        if (kn < Dd) {
#pragma unroll
            for (int q = 0; q < 2; ++q) {
                aReg[q] = *(const float4*)&A[(size_t)(m0 + am[q]) * Dd + kn + ak[q]];
                wReg[q] = *(const float4*)&W[(size_t)(kn + wk[q]) * Dd + n0 + wn[q]];
            }
        }
#pragma unroll
        for (int k = 0; k < BKk; ++k) {
            float a[8], b[8];
            *(float4*)&a[0] = *(float4*)&As[k][ty * 8];
            *(float4*)&a[4] = *(float4*)&As[k][ty * 8 + 4];
            *(float4*)&b[0] = *(float4*)&Ws[k][tx * 8];
            *(float4*)&b[4] = *(float4*)&Ws[k][tx * 8 + 4];
#pragma unroll
            for (int i = 0; i < 8; ++i)
#pragma unroll
                for (int j = 0; j < 8; ++j) acc[i][j] += a[i] * b[j];
        }
    }

    float bv[8];
#pragma unroll
    for (int j = 0; j < 8; ++j) bv[j] = bias[n0 + tx * 8 + j];
#pragma unroll
    for (int i = 0; i < 8; ++i) {
        int m = m0 + ty * 8 + i;
        float4 v0, v1;
        v0.x = fmaxf(acc[i][0] + bv[0], 0.f);
        v0.y = fmaxf(acc[i][1] + bv[1], 0.f);
        v0.z = fmaxf(acc[i][2] + bv[2], 0.f);
        v0.w = fmaxf(acc[i][3] + bv[3], 0.f);
        v1.x = fmaxf(acc[i][4] + bv[4], 0.f);
        v1.y = fmaxf(acc[i][5] + bv[5], 0.f);
        v1.z = fmaxf(acc[i][6] + bv[6], 0.f);
        v1.w = fmaxf(acc[i][7] + bv[7], 0.f);
        *(float4*)&C[(size_t)m * Dd + n0 + tx * 8]     = v0;
        *(float4*)&C[(size_t)m * Dd + n0 + tx * 8 + 4] = v1;
    }
}

// ---------------------------------------------------------------- gate: softmax(g @ gate_w + gb)
__global__ __launch_bounds__(256) void gate_kernel(const float* __restrict__ g,
                                                   const float* __restrict__ gw,
                                                   const float* __restrict__ gb,
                                                   float* __restrict__ wgt)
{
    int b = blockIdx.x;
    int tid = threadIdx.x;
    int lane = tid & 63;
    int wv = tid >> 6;

    float acc[16];
#pragma unroll
    for (int j = 0; j < 16; ++j) acc[j] = 0.f;

    const float* grow = g + (size_t)b * Dd;
#pragma unroll
    for (int it = 0; it < Dd / 256; ++it) {
        int d = tid + it * 256;
        float gv = grow[d];
        const float4* wr = (const float4*)(gw + (size_t)d * 16);
        float4 w0 = wr[0], w1 = wr[1], w2 = wr[2], w3 = wr[3];
        acc[0] += gv * w0.x;  acc[1] += gv * w0.y;  acc[2] += gv * w0.z;  acc[3] += gv * w0.w;
        acc[4] += gv * w1.x;  acc[5] += gv * w1.y;  acc[6] += gv * w1.z;  acc[7] += gv * w1.w;
        acc[8] += gv * w2.x;  acc[9] += gv * w2.y;  acc[10] += gv * w2.z; acc[11] += gv * w2.w;
        acc[12] += gv * w3.x; acc[13] += gv * w3.y; acc[14] += gv * w3.z; acc[15] += gv * w3.w;
    }

    __shared__ float red[64];
    __shared__ float logits[16];
#pragma unroll
    for (int j = 0; j < 16; ++j) {
        float v = acc[j];
#pragma unroll
        for (int m = 32; m >= 1; m >>= 1) v += __shfl_xor(v, m);
        if (lane == 0) red[wv * 16 + j] = v;
    }
    __syncthreads();
    if (tid < 16) {
        logits[tid] = gb[tid] + red[tid] + red[16 + tid] + red[32 + tid] + red[48 + tid];
    }
    __syncthreads();
    if (tid == 0) {
        float m = logits[0];
#pragma unroll
        for (int j = 1; j < 16; ++j) m = fmaxf(m, logits[j]);
        float ex[16], s = 0.f;
#pragma unroll
        for (int j = 0; j < 16; ++j) { ex[j] = __expf(logits[j] - m); s += ex[j]; }
        float inv = 1.f / s;
#pragma unroll
        for (int j = 0; j < 16; ++j) wgt[(size_t)b * 16 + j] = ex[j] * inv;
    }
}

// ---------------------------------------------------------------- fused 2-layer LSTM scan per expert
// grid = 256 blocks: block = (expert e, batch chunk of 64). 4 waves; lane=batch row,
// wave w owns units [5w,5w+5). Weights come from the packed buffer: each needed
// 20-col row slice is contiguous -> 5 float4 loads (wave-uniform address).
__global__ __launch_bounds__(256, 1) void lstm_kernel(
    const float* __restrict__ xn, const float* __restrict__ pw,
    const float* __restrict__ dw, const float* __restrict__ db,
    float* __restrict__ eo)
{
    const int e   = blockIdx.x >> 4;
    const int b0  = (blockIdx.x & 15) * 64;
    const int tid = threadIdx.x;
    const int lane = tid & 63;
    const int wv  = __builtin_amdgcn_readfirstlane(tid >> 6);

    __shared__ float xs[2][Ff][65];     // pad 65: staging writes conflict-free
    __shared__ float h1s[2][Hh][64];
    __shared__ float h2s[2][Hh][64];

    const float* W = pw + (size_t)((e << 2) + wv) * PWSZ;

    float b1r[20], b2r[20];
#pragma unroll
    for (int c = 0; c < 20; c += 4) {
        *(float4*)&b1r[c] = *(const float4*)&W[1840 + c];
        *(float4*)&b2r[c] = *(const float4*)&W[1860 + c];
    }

    for (int i = tid; i < Hh * 64; i += 256) {
        (&h1s[0][0][0])[i] = 0.f;
        (&h2s[0][0][0])[i] = 0.f;
    }

    float c1r[5] = {0, 0, 0, 0, 0}, c2r[5] = {0, 0, 0, 0, 0};

#pragma unroll 1
    for (int t = 0; t < Tt; ++t) {
        const int p = t & 1;
        // stage x_t transposed: xs[f][row]
#pragma unroll
        for (int q = 0; q < 2; ++q) {
            int id = tid + q * 256;
            int r  = id >> 3;
            int c4 = (id & 7) * 4;
            float4 v = *(const float4*)&xn[((size_t)(b0 + r) * Tt + t) * Ff + c4];
            xs[p][c4 + 0][r] = v.x;
            xs[p][c4 + 1][r] = v.y;
            xs[p][c4 + 2][r] = v.z;
            xs[p][c4 + 3][r] = v.w;
        }
        __syncthreads();  // A: x_t staged; h(t-1) visible

        float z1f[20], z2f[20];
#pragma unroll
        for (int c = 0; c < 20; ++c) { z1f[c] = b1r[c]; z2f[c] = b2r[c]; }

        // LSTM1 input projection
#pragma unroll
        for (int f = 0; f < Ff; ++f) {
            float xv = xs[p][f][lane];
            float wb[20];
#pragma unroll
            for (int c = 0; c < 20; c += 4) *(float4*)&wb[c] = *(const float4*)&W[f * 20 + c];
#pragma unroll
            for (int c = 0; c < 20; ++c) z1f[c] += xv * wb[c];
        }
        // recurrent for both layers (t-1 state)
#pragma unroll
        for (int k = 0; k < Hh; ++k) {
            float hv  = h1s[p][k][lane];
            float hv2 = h2s[p][k][lane];
            float w1b[20], w2b[20];
#pragma unroll
            for (int c = 0; c < 20; c += 4) {
                *(float4*)&w1b[c] = *(const float4*)&W[640  + k * 20 + c];
                *(float4*)&w2b[c] = *(const float4*)&W[1440 + k * 20 + c];
            }
#pragma unroll
            for (int c = 0; c < 20; ++c) { z1f[c] += hv * w1b[c]; z2f[c] += hv2 * w2b[c]; }
        }
        // LSTM1 elementwise -> h1(t)
#pragma unroll
        for (int u = 0; u < 5; ++u) {
            float iv = sigmoidf_(z1f[u]);
            float fv = sigmoidf_(z1f[5 + u]);
            float gv = fmaxf(z1f[10 + u], 0.f);
            float ov = sigmoidf_(z1f[15 + u]);
            float c  = fv * c1r[u] + iv * gv;
            c1r[u] = c;
            h1s[1 - p][wv * 5 + u][lane] = ov * fmaxf(c, 0.f);
        }
        __syncthreads();  // B: full h1(t) visible

        // LSTM2 input projection
#pragma unroll
        for (int k = 0; k < Hh; ++k) {
            float hv = h1s[1 - p][k][lane];
            float wb[20];
#pragma unroll
            for (int c = 0; c < 20; c += 4) *(float4*)&wb[c] = *(const float4*)&W[1040 + k * 20 + c];
#pragma unroll
            for (int c = 0; c < 20; ++c) z2f[c] += hv * wb[c];
        }
        // LSTM2 elementwise -> h2(t)
#pragma unroll
        for (int u = 0; u < 5; ++u) {
            float iv = sigmoidf_(z2f[u]);
            float fv = sigmoidf_(z2f[5 + u]);
            float gv = fmaxf(z2f[10 + u], 0.f);
            float ov = sigmoidf_(z2f[15 + u]);
            float c  = fv * c2r[u] + iv * gv;
            c2r[u] = c;
            h2s[1 - p][wv * 5 + u][lane] = ov * fmaxf(c, 0.f);
        }
    }
    __syncthreads();
    if (tid < 64) {  // final h2 in parity 0 (T even)
        float s = db[e];
#pragma unroll
        for (int k = 0; k < Hh; ++k) s += h2s[0][k][lane] * dw[e * Hh + k];
        eo[(size_t)e * Bsz + b0 + lane] = s;
    }
}

// ---------------------------------------------------------------- combine
__global__ void combine_kernel(const float* __restrict__ wgt,
                               const float* __restrict__ eo,
                               float* __restrict__ out)
{
    int b = blockIdx.x * blockDim.x + threadIdx.x;
    if (b < Bsz) {
        float s = 0.f;
#pragma unroll
        for (int e = 0; e < Ee; ++e) s += wgt[(size_t)b * 16 + e] * eo[(size_t)e * Bsz + b];
        out[b] = s;
    }
}

// ----------------------------------------------------------------
extern "C" void kernel_launch(void* const* d_in, const int* in_sizes, int n_in,
                              void* d_out, int out_size, void* d_ws, size_t ws_size,
                              hipStream_t stream)
{
    const float* x     = (const float*)d_in[0];
    const float* gamma = (const float*)d_in[1];
    const float* beta  = (const float*)d_in[2];
    const float* mean  = (const float*)d_in[3];
    const float* var   = (const float*)d_in[4];
    const float* k1    = (const float*)d_in[5];
    const float* r1    = (const float*)d_in[6];
    const float* b1    = (const float*)d_in[7];
    const float* k2    = (const float*)d_in[8];
    const float* r2    = (const float*)d_in[9];
    const float* b2    = (const float*)d_in[10];
    const float* dw    = (const float*)d_in[11];
    const float* db    = (const float*)d_in[12];
    const float* fc1w  = (const float*)d_in[13];
    const float* fc1b  = (const float*)d_in[14];
    const float* gw    = (const float*)d_in[15];
    const float* gb    = (const float*)d_in[16];
    float* out = (float*)d_out;

    float* xn  = (float*)d_ws;                    // 4,194,304 f
    float* g   = xn + (size_t)Bsz * Tt * Ff;      // 4,194,304 f
    float* wgt = g + (size_t)Bsz * Dd;            // 16,384 f
    float* eo  = wgt + (size_t)Bsz * Ee;          // 16,384 f
    float* pw  = eo + (size_t)Bsz * Ee;           // 120,320 f

    bn_kernel<<<1024, 256, 0, stream>>>(x, gamma, beta, mean, var, xn, Bsz * Tt * Ff / 4);
    repack_kernel<<<(Ee * 4 * PWSZ + 255) / 256, 256, 0, stream>>>(k1, r1, b1, k2, r2, b2, pw);
    lstm_kernel<<<256, 256, 0, stream>>>(xn, pw, dw, db, eo);
    fc1_gemm<<<dim3(Dd / BN, Bsz / BM), 256, 0, stream>>>(x, fc1w, fc1b, g);
    gate_kernel<<<Bsz, 256, 0, stream>>>(g, gw, gb, wgt);
    combine_kernel<<<4, 256, 0, stream>>>(wgt, eo, out);
}

// Round 3
// 1903.895 us; speedup vs baseline: 1.1124x; 1.0787x over previous
//
#include <hip/hip_runtime.h>
#include <math.h>

#define Bsz 1024
#define Tt  128
#define Ff  32
#define Ee  16
#define Hh  20
#define Dd  4096
#define EPSc 1e-3f

// packed-weight layout per (expert, wave): k1[32][20] @0, r1[20][20] @640,
// k2[20][20] @1040, r2[20][20] @1440, b1[20] @1840, b2[20] @1860 -> 1880 floats
#define PWSZ 1880

__device__ __forceinline__ float sigmoidf_(float x) {
    return 1.0f / (1.0f + __expf(-x));
}

// ---------------------------------------------------------------- BN (inference)
__global__ void bn_kernel(const float* __restrict__ x,
                          const float* __restrict__ gamma, const float* __restrict__ beta,
                          const float* __restrict__ mean,  const float* __restrict__ var,
                          float* __restrict__ xn, int n4)
{
    __shared__ float sc[Ff], sh[Ff];
    int tid = threadIdx.x;
    if (tid < Ff) {
        float s = gamma[tid] * rsqrtf(var[tid] + EPSc);
        sc[tid] = s;
        sh[tid] = beta[tid] - mean[tid] * s;
    }
    __syncthreads();
    const float4* x4 = (const float4*)x;
    float4* o4 = (float4*)xn;
    for (int i = blockIdx.x * blockDim.x + tid; i < n4; i += gridDim.x * blockDim.x) {
        float4 v = x4[i];
        int f0 = (i & 7) * 4;
        v.x = v.x * sc[f0 + 0] + sh[f0 + 0];
        v.y = v.y * sc[f0 + 1] + sh[f0 + 1];
        v.z = v.z * sc[f0 + 2] + sh[f0 + 2];
        v.w = v.w * sc[f0 + 3] + sh[f0 + 3];
        o4[i] = v;
    }
}

// ---------------------------------------------------------------- weight repack for lstm
__global__ void repack_kernel(const float* __restrict__ k1, const float* __restrict__ r1,
                              const float* __restrict__ b1, const float* __restrict__ k2,
                              const float* __restrict__ r2, const float* __restrict__ b2,
                              float* __restrict__ pw)
{
    int idx = blockIdx.x * blockDim.x + threadIdx.x;
    if (idx >= Ee * 4 * PWSZ) return;
    int ew = idx / PWSZ;
    int o  = idx % PWSZ;
    int e = ew >> 2, w = ew & 3;
    float v;
    if (o < 640) {
        int f = o / 20, c = o % 20, gg = c / 5, u = c % 5;
        v = k1[((size_t)e * Ff + f) * 80 + gg * 20 + w * 5 + u];
    } else if (o < 1040) {
        int k = (o - 640) / 20, c = (o - 640) % 20, gg = c / 5, u = c % 5;
        v = r1[((size_t)e * Hh + k) * 80 + gg * 20 + w * 5 + u];
    } else if (o < 1440) {
        int k = (o - 1040) / 20, c = (o - 1040) % 20, gg = c / 5, u = c % 5;
        v = k2[((size_t)e * Hh + k) * 80 + gg * 20 + w * 5 + u];
    } else if (o < 1840) {
        int k = (o - 1440) / 20, c = (o - 1440) % 20, gg = c / 5, u = c % 5;
        v = r2[((size_t)e * Hh + k) * 80 + gg * 20 + w * 5 + u];
    } else if (o < 1860) {
        int c = o - 1840, gg = c / 5, u = c % 5;
        v = b1[(size_t)e * 80 + gg * 20 + w * 5 + u];
    } else {
        int c = o - 1860, gg = c / 5, u = c % 5;
        v = b2[(size_t)e * 80 + gg * 20 + w * 5 + u];
    }
    pw[idx] = v;
}

// ---------------------------------------------------------------- fc1: relu(A@W + b), fp32 SGEMM
#define BM 128
#define BN 128
#define BKk 16
__global__ __launch_bounds__(256) void fc1_gemm(const float* __restrict__ A,
                                                const float* __restrict__ W,
                                                const float* __restrict__ bias,
                                                float* __restrict__ C)
{
    __shared__ float As[BKk][BM];
    __shared__ float Ws[BKk][BN];
    int tid = threadIdx.x;
    int m0 = blockIdx.y * BM;
    int n0 = blockIdx.x * BN;
    int tx = tid & 15, ty = tid >> 4;

    int am[2], ak[2], wk[2], wn[2];
#pragma unroll
    for (int q = 0; q < 2; ++q) {
        int id = tid + q * 256;
        am[q] = id >> 2;
        ak[q] = (id & 3) * 4;
        wk[q] = id >> 5;
        wn[q] = (id & 31) * 4;
    }

    float acc[8][8];
#pragma unroll
    for (int i = 0; i < 8; ++i)
#pragma unroll
        for (int j = 0; j < 8; ++j) acc[i][j] = 0.f;

    float4 aReg[2], wReg[2];
#pragma unroll
    for (int q = 0; q < 2; ++q) {
        aReg[q] = *(const float4*)&A[(size_t)(m0 + am[q]) * Dd + 0 + ak[q]];
        wReg[q] = *(const float4*)&W[(size_t)(0 + wk[q]) * Dd + n0 + wn[q]];
    }

    for (int k0 = 0; k0 < Dd; k0 += BKk) {
        __syncthreads();
#pragma unroll
        for (int q = 0; q < 2; ++q) {
            As[ak[q] + 0][am[q]] = aReg[q].x;
            As[ak[q] + 1][am[q]] = aReg[q].y;
            As[ak[q] + 2][am[q]] = aReg[q].z;
            As[ak[q] + 3][am[q]] = aReg[q].w;
            *(float4*)&Ws[wk[q]][wn[q]] = wReg[q];
        }
        __syncthreads();
        int kn = k0 + BKk;
        if (kn < Dd) {
#pragma unroll
            for (int q = 0; q < 2; ++q) {
                aReg[q] = *(const float4*)&A[(size_t)(m0 + am[q]) * Dd + kn + ak[q]];
                wReg[q] = *(const float4*)&W[(size_t)(kn + wk[q]) * Dd + n0 + wn[q]];
            }
        }
#pragma unroll
        for (int k = 0; k < BKk; ++k) {
            float a[8], b[8];
            *(float4*)&a[0] = *(float4*)&As[k][ty * 8];
            *(float4*)&a[4] = *(float4*)&As[k][ty * 8 + 4];
            *(float4*)&b[0] = *(float4*)&Ws[k][tx * 8];
            *(float4*)&b[4] = *(float4*)&Ws[k][tx * 8 + 4];
#pragma unroll
            for (int i = 0; i < 8; ++i)
#pragma unroll
                for (int j = 0; j < 8; ++j) acc[i][j] += a[i] * b[j];
        }
    }

    float bv[8];
#pragma unroll
    for (int j = 0; j < 8; ++j) bv[j] = bias[n0 + tx * 8 + j];
#pragma unroll
    for (int i = 0; i < 8; ++i) {
        int m = m0 + ty * 8 + i;
        float4 v0, v1;
        v0.x = fmaxf(acc[i][0] + bv[0], 0.f);
        v0.y = fmaxf(acc[i][1] + bv[1], 0.f);
        v0.z = fmaxf(acc[i][2] + bv[2], 0.f);
        v0.w = fmaxf(acc[i][3] + bv[3], 0.f);
        v1.x = fmaxf(acc[i][4] + bv[4], 0.f);
        v1.y = fmaxf(acc[i][5] + bv[5], 0.f);
        v1.z = fmaxf(acc[i][6] + bv[6], 0.f);
        v1.w = fmaxf(acc[i][7] + bv[7], 0.f);
        *(float4*)&C[(size_t)m * Dd + n0 + tx * 8]     = v0;
        *(float4*)&C[(size_t)m * Dd + n0 + tx * 8 + 4] = v1;
    }
}

// ---------------------------------------------------------------- gate: softmax(g @ gate_w + gb)
__global__ __launch_bounds__(256) void gate_kernel(const float* __restrict__ g,
                                                   const float* __restrict__ gw,
                                                   const float* __restrict__ gb,
                                                   float* __restrict__ wgt)
{
    int b = blockIdx.x;
    int tid = threadIdx.x;
    int lane = tid & 63;
    int wv = tid >> 6;

    float acc[16];
#pragma unroll
    for (int j = 0; j < 16; ++j) acc[j] = 0.f;

    const float* grow = g + (size_t)b * Dd;
#pragma unroll
    for (int it = 0; it < Dd / 256; ++it) {
        int d = tid + it * 256;
        float gv = grow[d];
        const float4* wr = (const float4*)(gw + (size_t)d * 16);
        float4 w0 = wr[0], w1 = wr[1], w2 = wr[2], w3 = wr[3];
        acc[0] += gv * w0.x;  acc[1] += gv * w0.y;  acc[2] += gv * w0.z;  acc[3] += gv * w0.w;
        acc[4] += gv * w1.x;  acc[5] += gv * w1.y;  acc[6] += gv * w1.z;  acc[7] += gv * w1.w;
        acc[8] += gv * w2.x;  acc[9] += gv * w2.y;  acc[10] += gv * w2.z; acc[11] += gv * w2.w;
        acc[12] += gv * w3.x; acc[13] += gv * w3.y; acc[14] += gv * w3.z; acc[15] += gv * w3.w;
    }

    __shared__ float red[64];
    __shared__ float logits[16];
#pragma unroll
    for (int j = 0; j < 16; ++j) {
        float v = acc[j];
#pragma unroll
        for (int m = 32; m >= 1; m >>= 1) v += __shfl_xor(v, m);
        if (lane == 0) red[wv * 16 + j] = v;
    }
    __syncthreads();
    if (tid < 16) {
        logits[tid] = gb[tid] + red[tid] + red[16 + tid] + red[32 + tid] + red[48 + tid];
    }
    __syncthreads();
    if (tid == 0) {
        float m = logits[0];
#pragma unroll
        for (int j = 1; j < 16; ++j) m = fmaxf(m, logits[j]);
        float ex[16], s = 0.f;
#pragma unroll
        for (int j = 0; j < 16; ++j) { ex[j] = __expf(logits[j] - m); s += ex[j]; }
        float inv = 1.f / s;
#pragma unroll
        for (int j = 0; j < 16; ++j) wgt[(size_t)b * 16 + j] = ex[j] * inv;
    }
}

// ---------------------------------------------------------------- fused 2-layer LSTM scan per expert
// grid = 256 blocks: block = (expert e, batch chunk of 64). 4 waves; lane=batch row,
// wave w owns units [5w,5w+5). All weights+biases staged to LDS once; in-loop weight
// reads are wave-uniform ds_read_b128 broadcasts (no VMEM in the hot loop).
__global__ __launch_bounds__(256, 1) void lstm_kernel(
    const float* __restrict__ xn, const float* __restrict__ pw,
    const float* __restrict__ dw, const float* __restrict__ db,
    float* __restrict__ eo)
{
    const int e   = blockIdx.x >> 4;
    const int b0  = (blockIdx.x & 15) * 64;
    const int tid = threadIdx.x;
    const int lane = tid & 63;
    const int wv  = __builtin_amdgcn_readfirstlane(tid >> 6);

    __shared__ float wlds[4 * PWSZ];    // 30,080 B: all 4 waves' packed weights
    __shared__ float xs[2][Ff][65];     // pad 65: staging writes conflict-free
    __shared__ float h1s[2][Hh][64];
    __shared__ float h2s[2][Hh][64];

    // stage weights to LDS (one time)
    {
        const float* src = pw + (size_t)(e << 2) * PWSZ;
        for (int i = tid; i < 4 * PWSZ; i += 256) wlds[i] = src[i];
    }
    for (int i = tid; i < Hh * 64; i += 256) {
        (&h1s[0][0][0])[i] = 0.f;
        (&h2s[0][0][0])[i] = 0.f;
    }

    const float* W = &wlds[wv * PWSZ];

    float c1r[5] = {0, 0, 0, 0, 0}, c2r[5] = {0, 0, 0, 0, 0};

#pragma unroll 1
    for (int t = 0; t < Tt; ++t) {
        const int p = t & 1;
        // stage x_t transposed: xs[f][row]
#pragma unroll
        for (int q = 0; q < 2; ++q) {
            int id = tid + q * 256;
            int r  = id >> 3;
            int c4 = (id & 7) * 4;
            float4 v = *(const float4*)&xn[((size_t)(b0 + r) * Tt + t) * Ff + c4];
            xs[p][c4 + 0][r] = v.x;
            xs[p][c4 + 1][r] = v.y;
            xs[p][c4 + 2][r] = v.z;
            xs[p][c4 + 3][r] = v.w;
        }
        __syncthreads();  // A: x_t + (t=0) weights staged; h(t-1) visible

        float z1f[20], z2f[20];
#pragma unroll
        for (int c = 0; c < 20; c += 4) {
            *(float4*)&z1f[c] = *(const float4*)&W[1840 + c];
            *(float4*)&z2f[c] = *(const float4*)&W[1860 + c];
        }

        // LSTM1 input projection
#pragma unroll
        for (int f = 0; f < Ff; ++f) {
            float xv = xs[p][f][lane];
            float wb[20];
#pragma unroll
            for (int c = 0; c < 20; c += 4) *(float4*)&wb[c] = *(const float4*)&W[f * 20 + c];
#pragma unroll
            for (int c = 0; c < 20; ++c) z1f[c] += xv * wb[c];
        }
        // recurrent for both layers (t-1 state)
#pragma unroll
        for (int k = 0; k < Hh; ++k) {
            float hv  = h1s[p][k][lane];
            float hv2 = h2s[p][k][lane];
            float w1b[20], w2b[20];
#pragma unroll
            for (int c = 0; c < 20; c += 4) {
                *(float4*)&w1b[c] = *(const float4*)&W[640  + k * 20 + c];
                *(float4*)&w2b[c] = *(const float4*)&W[1440 + k * 20 + c];
            }
#pragma unroll
            for (int c = 0; c < 20; ++c) { z1f[c] += hv * w1b[c]; z2f[c] += hv2 * w2b[c]; }
        }
        // LSTM1 elementwise -> h1(t)
#pragma unroll
        for (int u = 0; u < 5; ++u) {
            float iv = sigmoidf_(z1f[u]);
            float fv = sigmoidf_(z1f[5 + u]);
            float gv = fmaxf(z1f[10 + u], 0.f);
            float ov = sigmoidf_(z1f[15 + u]);
            float c  = fv * c1r[u] + iv * gv;
            c1r[u] = c;
            h1s[1 - p][wv * 5 + u][lane] = ov * fmaxf(c, 0.f);
        }
        __syncthreads();  // B: full h1(t) visible

        // LSTM2 input projection
#pragma unroll
        for (int k = 0; k < Hh; ++k) {
            float hv = h1s[1 - p][k][lane];
            float wb[20];
#pragma unroll
            for (int c = 0; c < 20; c += 4) *(float4*)&wb[c] = *(const float4*)&W[1040 + k * 20 + c];
#pragma unroll
            for (int c = 0; c < 20; ++c) z2f[c] += hv * wb[c];
        }
        // LSTM2 elementwise -> h2(t)
#pragma unroll
        for (int u = 0; u < 5; ++u) {
            float iv = sigmoidf_(z2f[u]);
            float fv = sigmoidf_(z2f[5 + u]);
            float gv = fmaxf(z2f[10 + u], 0.f);
            float ov = sigmoidf_(z2f[15 + u]);
            float c  = fv * c2r[u] + iv * gv;
            c2r[u] = c;
            h2s[1 - p][wv * 5 + u][lane] = ov * fmaxf(c, 0.f);
        }
    }
    __syncthreads();
    if (tid < 64) {  // final h2 in parity 0 (T even)
        float s = db[e];
#pragma unroll
        for (int k = 0; k < Hh; ++k) s += h2s[0][k][lane] * dw[e * Hh + k];
        eo[(size_t)e * Bsz + b0 + lane] = s;
    }
}

// ---------------------------------------------------------------- combine
__global__ void combine_kernel(const float* __restrict__ wgt,
                               const float* __restrict__ eo,
                               float* __restrict__ out)
{
    int b = blockIdx.x * blockDim.x + threadIdx.x;
    if (b < Bsz) {
        float s = 0.f;
#pragma unroll
        for (int e = 0; e < Ee; ++e) s += wgt[(size_t)b * 16 + e] * eo[(size_t)e * Bsz + b];
        out[b] = s;
    }
}

// ----------------------------------------------------------------
extern "C" void kernel_launch(void* const* d_in, const int* in_sizes, int n_in,
                              void* d_out, int out_size, void* d_ws, size_t ws_size,
                              hipStream_t stream)
{
    const float* x     = (const float*)d_in[0];
    const float* gamma = (const float*)d_in[1];
    const float* beta  = (const float*)d_in[2];
    const float* mean  = (const float*)d_in[3];
    const float* var   = (const float*)d_in[4];
    const float* k1    = (const float*)d_in[5];
    const float* r1    = (const float*)d_in[6];
    const float* b1    = (const float*)d_in[7];
    const float* k2    = (const float*)d_in[8];
    const float* r2    = (const float*)d_in[9];
    const float* b2    = (const float*)d_in[10];
    const float* dw    = (const float*)d_in[11];
    const float* db    = (const float*)d_in[12];
    const float* fc1w  = (const float*)d_in[13];
    const float* fc1b  = (const float*)d_in[14];
    const float* gw    = (const float*)d_in[15];
    const float* gb    = (const float*)d_in[16];
    float* out = (float*)d_out;

    float* xn  = (float*)d_ws;                    // 4,194,304 f
    float* g   = xn + (size_t)Bsz * Tt * Ff;      // 4,194,304 f
    float* wgt = g + (size_t)Bsz * Dd;            // 16,384 f
    float* eo  = wgt + (size_t)Bsz * Ee;          // 16,384 f
    float* pw  = eo + (size_t)Bsz * Ee;           // 120,320 f

    bn_kernel<<<1024, 256, 0, stream>>>(x, gamma, beta, mean, var, xn, Bsz * Tt * Ff / 4);
    repack_kernel<<<(Ee * 4 * PWSZ + 255) / 256, 256, 0, stream>>>(k1, r1, b1, k2, r2, b2, pw);
    lstm_kernel<<<256, 256, 0, stream>>>(xn, pw, dw, db, eo);
    fc1_gemm<<<dim3(Dd / BN, Bsz / BM), 256, 0, stream>>>(x, fc1w, fc1b, g);
    gate_kernel<<<Bsz, 256, 0, stream>>>(g, gw, gb, wgt);
    combine_kernel<<<4, 256, 0, stream>>>(wgt, eo, out);
}

// Round 4
// 1162.948 us; speedup vs baseline: 1.8211x; 1.6371x over previous
//
#include <hip/hip_runtime.h>
#include <math.h>

#define Bsz 1024
#define Tt  128
#define Ff  32
#define Ee  16
#define Hh  20
#define Dd  4096
#define EPSc 1e-3f

// repacked fp32 weights per expert, gate-interleaved cols c = 4*u + g (g: i,f,g,o):
// K1p[32][80]@0, R1p[20][80]@2560, K2p[20][80]@4160, R2p[20][80]@5760,
// b1p[80]@7360, b2p[80]@7440  -> 7520 floats per expert
#define PWE 7520

typedef __attribute__((ext_vector_type(8))) short bf16x8;
typedef __attribute__((ext_vector_type(4))) float f32x4;

#define MFMA16(a,b,c) __builtin_amdgcn_mfma_f32_16x16x32_bf16(a, b, c, 0, 0, 0)

__device__ __forceinline__ float sigmoidf_(float x) {
    return 1.0f / (1.0f + __expf(-x));
}
__device__ __forceinline__ unsigned short bf16_rne(float f) {
    unsigned u = __float_as_uint(f);
    u += 0x7FFFu + ((u >> 16) & 1u);
    return (unsigned short)(u >> 16);
}
__device__ __forceinline__ float bf16_to_f(unsigned short h) {
    return __uint_as_float(((unsigned)h) << 16);
}

// ---------------------------------------------------------------- BN (inference)
__global__ void bn_kernel(const float* __restrict__ x,
                          const float* __restrict__ gamma, const float* __restrict__ beta,
                          const float* __restrict__ mean,  const float* __restrict__ var,
                          float* __restrict__ xn, int n4)
{
    __shared__ float sc[Ff], sh[Ff];
    int tid = threadIdx.x;
    if (tid < Ff) {
        float s = gamma[tid] * rsqrtf(var[tid] + EPSc);
        sc[tid] = s;
        sh[tid] = beta[tid] - mean[tid] * s;
    }
    __syncthreads();
    const float4* x4 = (const float4*)x;
    float4* o4 = (float4*)xn;
    for (int i = blockIdx.x * blockDim.x + tid; i < n4; i += gridDim.x * blockDim.x) {
        float4 v = x4[i];
        int f0 = (i & 7) * 4;
        v.x = v.x * sc[f0 + 0] + sh[f0 + 0];
        v.y = v.y * sc[f0 + 1] + sh[f0 + 1];
        v.z = v.z * sc[f0 + 2] + sh[f0 + 2];
        v.w = v.w * sc[f0 + 3] + sh[f0 + 3];
        o4[i] = v;
    }
}

// ---------------------------------------------------------------- weight repack (gate-interleave)
__global__ void repack2_kernel(const float* __restrict__ k1, const float* __restrict__ r1,
                               const float* __restrict__ b1, const float* __restrict__ k2,
                               const float* __restrict__ r2, const float* __restrict__ b2,
                               float* __restrict__ pw)
{
    int idx = blockIdx.x * blockDim.x + threadIdx.x;
    if (idx >= Ee * PWE) return;
    int e = idx / PWE;
    int o = idx % PWE;
    float v;
    if (o < 7360) {
        int c = o % 80, u = c >> 2, g = c & 3;
        int co = g * 20 + u;
        if (o < 2560) {
            int kk = o / 80;
            v = k1[((size_t)e * Ff + kk) * 80 + co];
        } else if (o < 4160) {
            int kk = (o - 2560) / 80;
            v = r1[((size_t)e * Hh + kk) * 80 + co];
        } else if (o < 5760) {
            int kk = (o - 4160) / 80;
            v = k2[((size_t)e * Hh + kk) * 80 + co];
        } else {
            int kk = (o - 5760) / 80;
            v = r2[((size_t)e * Hh + kk) * 80 + co];
        }
    } else if (o < 7440) {
        int c = o - 7360, u = c >> 2, g = c & 3;
        v = b1[(size_t)e * 80 + g * 20 + u];
    } else {
        int c = o - 7440, u = c >> 2, g = c & 3;
        v = b2[(size_t)e * 80 + g * 20 + u];
    }
    pw[idx] = v;
}

// ---------------------------------------------------------------- fc1: relu(A@W + b), fp32 SGEMM
#define BM 128
#define BN 128
#define BKk 16
__global__ __launch_bounds__(256) void fc1_gemm(const float* __restrict__ A,
                                                const float* __restrict__ W,
                                                const float* __restrict__ bias,
                                                float* __restrict__ C)
{
    __shared__ float As[BKk][BM];
    __shared__ float Ws[BKk][BN];
    int tid = threadIdx.x;
    int m0 = blockIdx.y * BM;
    int n0 = blockIdx.x * BN;
    int tx = tid & 15, ty = tid >> 4;

    int am[2], ak[2], wk[2], wn[2];
#pragma unroll
    for (int q = 0; q < 2; ++q) {
        int id = tid + q * 256;
        am[q] = id >> 2;
        ak[q] = (id & 3) * 4;
        wk[q] = id >> 5;
        wn[q] = (id & 31) * 4;
    }

    float acc[8][8];
#pragma unroll
    for (int i = 0; i < 8; ++i)
#pragma unroll
        for (int j = 0; j < 8; ++j) acc[i][j] = 0.f;

    float4 aReg[2], wReg[2];
#pragma unroll
    for (int q = 0; q < 2; ++q) {
        aReg[q] = *(const float4*)&A[(size_t)(m0 + am[q]) * Dd + 0 + ak[q]];
        wReg[q] = *(const float4*)&W[(size_t)(0 + wk[q]) * Dd + n0 + wn[q]];
    }

    for (int k0 = 0; k0 < Dd; k0 += BKk) {
        __syncthreads();
#pragma unroll
        for (int q = 0; q < 2; ++q) {
            As[ak[q] + 0][am[q]] = aReg[q].x;
            As[ak[q] + 1][am[q]] = aReg[q].y;
            As[ak[q] + 2][am[q]] = aReg[q].z;
            As[ak[q] + 3][am[q]] = aReg[q].w;
            *(float4*)&Ws[wk[q]][wn[q]] = wReg[q];
        }
        __syncthreads();
        int kn = k0 + BKk;
        if (kn < Dd) {
#pragma unroll
            for (int q = 0; q < 2; ++q) {
                aReg[q] = *(const float4*)&A[(size_t)(m0 + am[q]) * Dd + kn + ak[q]];
                wReg[q] = *(const float4*)&W[(size_t)(kn + wk[q]) * Dd + n0 + wn[q]];
            }
        }
#pragma unroll
        for (int k = 0; k < BKk; ++k) {
            float a[8], b[8];
            *(float4*)&a[0] = *(float4*)&As[k][ty * 8];
            *(float4*)&a[4] = *(float4*)&As[k][ty * 8 + 4];
            *(float4*)&b[0] = *(float4*)&Ws[k][tx * 8];
            *(float4*)&b[4] = *(float4*)&Ws[k][tx * 8 + 4];
#pragma unroll
            for (int i = 0; i < 8; ++i)
#pragma unroll
                for (int j = 0; j < 8; ++j) acc[i][j] += a[i] * b[j];
        }
    }

    float bv[8];
#pragma unroll
    for (int j = 0; j < 8; ++j) bv[j] = bias[n0 + tx * 8 + j];
#pragma unroll
    for (int i = 0; i < 8; ++i) {
        int m = m0 + ty * 8 + i;
        float4 v0, v1;
        v0.x = fmaxf(acc[i][0] + bv[0], 0.f);
        v0.y = fmaxf(acc[i][1] + bv[1], 0.f);
        v0.z = fmaxf(acc[i][2] + bv[2], 0.f);
        v0.w = fmaxf(acc[i][3] + bv[3], 0.f);
        v1.x = fmaxf(acc[i][4] + bv[4], 0.f);
        v1.y = fmaxf(acc[i][5] + bv[5], 0.f);
        v1.z = fmaxf(acc[i][6] + bv[6], 0.f);
        v1.w = fmaxf(acc[i][7] + bv[7], 0.f);
        *(float4*)&C[(size_t)m * Dd + n0 + tx * 8]     = v0;
        *(float4*)&C[(size_t)m * Dd + n0 + tx * 8 + 4] = v1;
    }
}

// ---------------------------------------------------------------- gate: softmax(g @ gate_w + gb)
__global__ __launch_bounds__(256) void gate_kernel(const float* __restrict__ g,
                                                   const float* __restrict__ gw,
                                                   const float* __restrict__ gb,
                                                   float* __restrict__ wgt)
{
    int b = blockIdx.x;
    int tid = threadIdx.x;
    int lane = tid & 63;
    int wv = tid >> 6;

    float acc[16];
#pragma unroll
    for (int j = 0; j < 16; ++j) acc[j] = 0.f;

    const float* grow = g + (size_t)b * Dd;
#pragma unroll
    for (int it = 0; it < Dd / 256; ++it) {
        int d = tid + it * 256;
        float gv = grow[d];
        const float4* wr = (const float4*)(gw + (size_t)d * 16);
        float4 w0 = wr[0], w1 = wr[1], w2 = wr[2], w3 = wr[3];
        acc[0] += gv * w0.x;  acc[1] += gv * w0.y;  acc[2] += gv * w0.z;  acc[3] += gv * w0.w;
        acc[4] += gv * w1.x;  acc[5] += gv * w1.y;  acc[6] += gv * w1.z;  acc[7] += gv * w1.w;
        acc[8] += gv * w2.x;  acc[9] += gv * w2.y;  acc[10] += gv * w2.z; acc[11] += gv * w2.w;
        acc[12] += gv * w3.x; acc[13] += gv * w3.y; acc[14] += gv * w3.z; acc[15] += gv * w3.w;
    }

    __shared__ float red[64];
    __shared__ float logits[16];
#pragma unroll
    for (int j = 0; j < 16; ++j) {
        float v = acc[j];
#pragma unroll
        for (int m = 32; m >= 1; m >>= 1) v += __shfl_xor(v, m);
        if (lane == 0) red[wv * 16 + j] = v;
    }
    __syncthreads();
    if (tid < 16) {
        logits[tid] = gb[tid] + red[tid] + red[16 + tid] + red[32 + tid] + red[48 + tid];
    }
    __syncthreads();
    if (tid == 0) {
        float m = logits[0];
#pragma unroll
        for (int j = 1; j < 16; ++j) m = fmaxf(m, logits[j]);
        float ex[16], s = 0.f;
#pragma unroll
        for (int j = 0; j < 16; ++j) { ex[j] = __expf(logits[j] - m); s += ex[j]; }
        float inv = 1.f / s;
#pragma unroll
        for (int j = 0; j < 16; ++j) wgt[(size_t)b * 16 + j] = ex[j] * inv;
    }
}

// ---------------------------------------------------------------- MFMA split-bf16 2-layer LSTM
// grid = 1024 blocks of 64 threads (1 wave): block = (expert, 16-row batch chunk).
// Weights live in VGPRs as MFMA B-fragments (hi/lo split), loaded once.
// Per t: z = bias + A@W via mfma_f32_16x16x32_bf16 (3 mfma per term for hi/lo),
// C-layout -> LDS -> per-lane elementwise -> h written back as bf16 hi/lo A-frags.
// Single-wave workgroup: no barriers; LDS deps ordered by in-wave lgkmcnt.
__global__ __launch_bounds__(64, 1) void lstm_kernel(
    const float* __restrict__ xn, const float* __restrict__ pw,
    const float* __restrict__ dw, const float* __restrict__ db,
    float* __restrict__ eo)
{
    const int e  = blockIdx.x >> 6;
    const int b0 = (blockIdx.x & 63) * 16;
    const int l  = threadIdx.x;
    const int q  = l >> 4;     // quad: A-frag k-group / C-frag row-group
    const int s  = l & 15;     // C-frag col / A-frag row

    // A-layout activation buffers, bf16, [m=16][k<=32], row stride 40 shorts (80 B)
    __shared__ short xh[16 * 40], xlo[16 * 40];
    __shared__ short h1h[16 * 40], h1l[16 * 40];
    __shared__ short h2h[16 * 40], h2l[16 * 40];
    __shared__ float z1buf[16 * 84 + 4];   // [b][col], row stride 84 (16B-aligned rows)
    __shared__ float z2buf[16 * 84 + 4];

    // zero h state (incl. k=20..31 MFMA padding)
    for (int i = l; i < 16 * 40; i += 64) {
        h1h[i] = 0; h1l[i] = 0; h2h[i] = 0; h2l[i] = 0;
    }

    const float* Wm = pw + (size_t)e * PWE;

    // ---- preload weight B-fragments: lane holds B[k=q*8+j][n*16+s]
    bf16x8 K1h[5], K1l[5], R1h[5], R1l[5], K2h[5], K2l[5], R2h[5], R2l[5];
#pragma unroll
    for (int n = 0; n < 5; ++n) {
#pragma unroll
        for (int j = 0; j < 8; ++j) {
            int k = q * 8 + j;
            int c = n * 16 + s;
            float w;
            unsigned short hi; float hf;
            w = Wm[k * 80 + c];                                 // K1, K=32
            hi = bf16_rne(w); hf = bf16_to_f(hi);
            K1h[n][j] = (short)hi; K1l[n][j] = (short)bf16_rne(w - hf);
            w = (k < Hh) ? Wm[2560 + k * 80 + c] : 0.f;         // R1, K=20
            hi = bf16_rne(w); hf = bf16_to_f(hi);
            R1h[n][j] = (short)hi; R1l[n][j] = (short)bf16_rne(w - hf);
            w = (k < Hh) ? Wm[4160 + k * 80 + c] : 0.f;         // K2
            hi = bf16_rne(w); hf = bf16_to_f(hi);
            K2h[n][j] = (short)hi; K2l[n][j] = (short)bf16_rne(w - hf);
            w = (k < Hh) ? Wm[5760 + k * 80 + c] : 0.f;         // R2
            hi = bf16_rne(w); hf = bf16_to_f(hi);
            R2h[n][j] = (short)hi; R2l[n][j] = (short)bf16_rne(w - hf);
        }
    }
    float bv1[5], bv2[5], dwr[5];
#pragma unroll
    for (int n = 0; n < 5; ++n) {
        bv1[n] = Wm[7360 + n * 16 + s];
        bv2[n] = Wm[7440 + n * 16 + s];
    }
#pragma unroll
    for (int i = 0; i < 5; ++i) dwr[i] = dw[e * Hh + 4 * i + q];

    float c1[5] = {0, 0, 0, 0, 0}, c2[5] = {0, 0, 0, 0, 0};
    float h2reg[5] = {0, 0, 0, 0, 0};

    const int row = l >> 2, fc = l & 3;           // x staging: lane covers 8 f of one row
    const float* xbase = xn + ((size_t)(b0 + row) * Tt) * Ff + fc * 8;

#pragma unroll 1
    for (int t = 0; t < Tt; ++t) {
        // ---- stage x_t as bf16 hi/lo A-frags
        {
            float4 xa = *(const float4*)(xbase + (size_t)t * Ff);
            float4 xb = *(const float4*)(xbase + (size_t)t * Ff + 4);
            float xv[8] = {xa.x, xa.y, xa.z, xa.w, xb.x, xb.y, xb.z, xb.w};
            bf16x8 hv, lv;
#pragma unroll
            for (int j = 0; j < 8; ++j) {
                unsigned short hi = bf16_rne(xv[j]);
                hv[j] = (short)hi;
                lv[j] = (short)bf16_rne(xv[j] - bf16_to_f(hi));
            }
            *(bf16x8*)&xh[row * 40 + fc * 8]  = hv;
            *(bf16x8*)&xlo[row * 40 + fc * 8] = lv;
        }
        // ---- read A-frags (x_t, h1(t-1), h2(t-1))
        bf16x8 Xh  = *(bf16x8*)&xh[s * 40 + q * 8];
        bf16x8 Xl  = *(bf16x8*)&xlo[s * 40 + q * 8];
        bf16x8 H1a = *(bf16x8*)&h1h[s * 40 + q * 8];
        bf16x8 H1b = *(bf16x8*)&h1l[s * 40 + q * 8];
        bf16x8 H2a = *(bf16x8*)&h2h[s * 40 + q * 8];
        bf16x8 H2b = *(bf16x8*)&h2l[s * 40 + q * 8];

        // ---- layer-1 gates
        f32x4 a1[5];
#pragma unroll
        for (int n = 0; n < 5; ++n) {
            f32x4 acc = {bv1[n], bv1[n], bv1[n], bv1[n]};
            acc = MFMA16(Xh,  K1h[n], acc);
            acc = MFMA16(Xh,  K1l[n], acc);
            acc = MFMA16(Xl,  K1h[n], acc);
            acc = MFMA16(H1a, R1h[n], acc);
            acc = MFMA16(H1a, R1l[n], acc);
            acc = MFMA16(H1b, R1h[n], acc);
            a1[n] = acc;
        }
#pragma unroll
        for (int n = 0; n < 5; ++n)
#pragma unroll
            for (int r = 0; r < 4; ++r)
                z1buf[(4 * q + r) * 84 + n * 16 + s] = a1[n][r];

        // ---- layer-1 elementwise: lane handles b=s, units u=4i+q
#pragma unroll
        for (int i = 0; i < 5; ++i) {
            int u = 4 * i + q;
            f32x4 zz = *(f32x4*)&z1buf[s * 84 + 4 * u];
            float iv = sigmoidf_(zz[0]);
            float fv = sigmoidf_(zz[1]);
            float gv = fmaxf(zz[2], 0.f);
            float ov = sigmoidf_(zz[3]);
            c1[i] = fv * c1[i] + iv * gv;
            float h = ov * fmaxf(c1[i], 0.f);
            unsigned short hi = bf16_rne(h);
            h1h[s * 40 + u] = (short)hi;
            h1l[s * 40 + u] = (short)bf16_rne(h - bf16_to_f(hi));
        }

        // ---- layer-2 gates (h1(t) and h2(t-1))
        bf16x8 H1c = *(bf16x8*)&h1h[s * 40 + q * 8];
        bf16x8 H1d = *(bf16x8*)&h1l[s * 40 + q * 8];
        f32x4 a2[5];
#pragma unroll
        for (int n = 0; n < 5; ++n) {
            f32x4 acc = {bv2[n], bv2[n], bv2[n], bv2[n]};
            acc = MFMA16(H1c, K2h[n], acc);
            acc = MFMA16(H1c, K2l[n], acc);
            acc = MFMA16(H1d, K2h[n], acc);
            acc = MFMA16(H2a, R2h[n], acc);
            acc = MFMA16(H2a, R2l[n], acc);
            acc = MFMA16(H2b, R2h[n], acc);
            a2[n] = acc;
        }
#pragma unroll
        for (int n = 0; n < 5; ++n)
#pragma unroll
            for (int r = 0; r < 4; ++r)
                z2buf[(4 * q + r) * 84 + n * 16 + s] = a2[n][r];

        // ---- layer-2 elementwise
#pragma unroll
        for (int i = 0; i < 5; ++i) {
            int u = 4 * i + q;
            f32x4 zz = *(f32x4*)&z2buf[s * 84 + 4 * u];
            float iv = sigmoidf_(zz[0]);
            float fv = sigmoidf_(zz[1]);
            float gv = fmaxf(zz[2], 0.f);
            float ov = sigmoidf_(zz[3]);
            c2[i] = fv * c2[i] + iv * gv;
            float h = ov * fmaxf(c2[i], 0.f);
            h2reg[i] = h;
            unsigned short hi = bf16_rne(h);
            h2h[s * 40 + u] = (short)hi;
            h2l[s * 40 + u] = (short)bf16_rne(h - bf16_to_f(hi));
        }
    }

    // ---- dense head: out = h2(T) @ dw + db ; reduce over u across quads
    float p = 0.f;
#pragma unroll
    for (int i = 0; i < 5; ++i) p += h2reg[i] * dwr[i];
    p += __shfl_xor(p, 16);
    p += __shfl_xor(p, 32);
    if (q == 0) eo[(size_t)e * Bsz + b0 + s] = db[e] + p;
}

// ---------------------------------------------------------------- combine
__global__ void combine_kernel(const float* __restrict__ wgt,
                               const float* __restrict__ eo,
                               float* __restrict__ out)
{
    int b = blockIdx.x * blockDim.x + threadIdx.x;
    if (b < Bsz) {
        float s = 0.f;
#pragma unroll
        for (int e = 0; e < Ee; ++e) s += wgt[(size_t)b * 16 + e] * eo[(size_t)e * Bsz + b];
        out[b] = s;
    }
}

// ----------------------------------------------------------------
extern "C" void kernel_launch(void* const* d_in, const int* in_sizes, int n_in,
                              void* d_out, int out_size, void* d_ws, size_t ws_size,
                              hipStream_t stream)
{
    const float* x     = (const float*)d_in[0];
    const float* gamma = (const float*)d_in[1];
    const float* beta  = (const float*)d_in[2];
    const float* mean  = (const float*)d_in[3];
    const float* var   = (const float*)d_in[4];
    const float* k1    = (const float*)d_in[5];
    const float* r1    = (const float*)d_in[6];
    const float* b1    = (const float*)d_in[7];
    const float* k2    = (const float*)d_in[8];
    const float* r2    = (const float*)d_in[9];
    const float* b2    = (const float*)d_in[10];
    const float* dw    = (const float*)d_in[11];
    const float* db    = (const float*)d_in[12];
    const float* fc1w  = (const float*)d_in[13];
    const float* fc1b  = (const float*)d_in[14];
    const float* gw    = (const float*)d_in[15];
    const float* gb    = (const float*)d_in[16];
    float* out = (float*)d_out;

    float* xn  = (float*)d_ws;                    // 4,194,304 f
    float* g   = xn + (size_t)Bsz * Tt * Ff;      // 4,194,304 f
    float* wgt = g + (size_t)Bsz * Dd;            // 16,384 f
    float* eo  = wgt + (size_t)Bsz * Ee;          // 16,384 f
    float* pw  = eo + (size_t)Bsz * Ee;           // 120,320 f

    bn_kernel<<<1024, 256, 0, stream>>>(x, gamma, beta, mean, var, xn, Bsz * Tt * Ff / 4);
    repack2_kernel<<<(Ee * PWE + 255) / 256, 256, 0, stream>>>(k1, r1, b1, k2, r2, b2, pw);
    lstm_kernel<<<1024, 64, 0, stream>>>(xn, pw, dw, db, eo);
    fc1_gemm<<<dim3(Dd / BN, Bsz / BM), 256, 0, stream>>>(x, fc1w, fc1b, g);
    gate_kernel<<<Bsz, 256, 0, stream>>>(g, gw, gb, wgt);
    combine_kernel<<<4, 256, 0, stream>>>(wgt, eo, out);
}

// Round 5
// 672.895 us; speedup vs baseline: 3.1474x; 1.7283x over previous
//
#include <hip/hip_runtime.h>
#include <math.h>

#define Bsz 1024
#define Tt  128
#define Ff  32
#define Ee  16
#define Hh  20
#define Dd  4096
#define EPSc 1e-3f

// repacked fp32 weights per expert, gate-interleaved cols c = 4*u + g (g: i,f,g,o):
// K1p[32][80]@0, R1p[20][80]@2560, K2p[20][80]@4160, R2p[20][80]@5760,
// b1p[80]@7360, b2p[80]@7440  -> 7520 floats per expert
#define PWE 7520

typedef __attribute__((ext_vector_type(8))) short bf16x8;
typedef __attribute__((ext_vector_type(4))) float f32x4;

#define MFMA16(a,b,c) __builtin_amdgcn_mfma_f32_16x16x32_bf16(a, b, c, 0, 0, 0)

__device__ __forceinline__ float sigmoidf_(float x) {
    return 1.0f / (1.0f + __expf(-x));
}
__device__ __forceinline__ unsigned short bf16_rne(float f) {
    unsigned u = __float_as_uint(f);
    u += 0x7FFFu + ((u >> 16) & 1u);
    return (unsigned short)(u >> 16);
}
__device__ __forceinline__ float bf16_to_f(unsigned short h) {
    return __uint_as_float(((unsigned)h) << 16);
}

// ---------------------------------------------------------------- A-convert: x -> bf16 hi/lo
__global__ void aconv_kernel(const float* __restrict__ x,
                             unsigned short* __restrict__ Ah,
                             unsigned short* __restrict__ Al, int n4)
{
    int i = blockIdx.x * blockDim.x + threadIdx.x;
    if (i >= n4) return;
    float4 v = ((const float4*)x)[i];
    ushort4 h, l;
    h.x = bf16_rne(v.x); l.x = bf16_rne(v.x - bf16_to_f(h.x));
    h.y = bf16_rne(v.y); l.y = bf16_rne(v.y - bf16_to_f(h.y));
    h.z = bf16_rne(v.z); l.z = bf16_rne(v.z - bf16_to_f(h.z));
    h.w = bf16_rne(v.w); l.w = bf16_rne(v.w - bf16_to_f(h.w));
    ((ushort4*)Ah)[i] = h;
    ((ushort4*)Al)[i] = l;
}

// ---------------------------------------------------------------- weight repack (gate-interleave)
__global__ void repack2_kernel(const float* __restrict__ k1, const float* __restrict__ r1,
                               const float* __restrict__ b1, const float* __restrict__ k2,
                               const float* __restrict__ r2, const float* __restrict__ b2,
                               float* __restrict__ pw)
{
    int idx = blockIdx.x * blockDim.x + threadIdx.x;
    if (idx >= Ee * PWE) return;
    int e = idx / PWE;
    int o = idx % PWE;
    float v;
    if (o < 7360) {
        int c = o % 80, u = c >> 2, g = c & 3;
        int co = g * 20 + u;
        if (o < 2560) {
            int kk = o / 80;
            v = k1[((size_t)e * Ff + kk) * 80 + co];
        } else if (o < 4160) {
            int kk = (o - 2560) / 80;
            v = r1[((size_t)e * Hh + kk) * 80 + co];
        } else if (o < 5760) {
            int kk = (o - 4160) / 80;
            v = k2[((size_t)e * Hh + kk) * 80 + co];
        } else {
            int kk = (o - 5760) / 80;
            v = r2[((size_t)e * Hh + kk) * 80 + co];
        }
    } else if (o < 7440) {
        int c = o - 7360, u = c >> 2, g = c & 3;
        v = b1[(size_t)e * 80 + g * 20 + u];
    } else {
        int c = o - 7440, u = c >> 2, g = c & 3;
        v = b2[(size_t)e * 80 + g * 20 + u];
    }
    pw[idx] = v;
}

// ---------------------------------------------------------------- fc1: relu(A@W + b) via split-bf16 MFMA
// C[1024][4096] = A[1024][4096] @ W[4096][4096].  A pre-split (Ah/Al bf16);
// W converted to hi/lo during LDS staging.  acc += Ah*Wh + Ah*Wl + Al*Wh.
// 128x128 tile, BK=32, 256 thr / 4 waves (each 64x64 quadrant, 4x4 16x16 frags).
__global__ __launch_bounds__(256, 1) void fc1_mfma(const unsigned short* __restrict__ Ah,
                                                   const unsigned short* __restrict__ Al,
                                                   const float* __restrict__ W,
                                                   const float* __restrict__ bias,
                                                   float* __restrict__ C)
{
    __shared__ unsigned short Ash[128 * 40], Asl[128 * 40];   // [m][k], row stride 40
    __shared__ unsigned short Wsh[128 * 40], Wsl[128 * 40];   // [n][k] (transposed)

    const int tid = threadIdx.x;
    const int wv = tid >> 6, l = tid & 63, q = l >> 4, s = l & 15;
    const int m0 = blockIdx.y * 128, n0 = blockIdx.x * 128;
    const int wr = (wv & 1) * 64, wc = (wv >> 1) * 64;

    // staging maps
    const int am = tid >> 1, ak = (tid & 1) * 16;     // A: row (0..127), k-offset (0/16)
    const int wn = tid & 127, wkq = tid >> 7;         // W: col n (0..127), k-half (0/1)

    const unsigned short* AhG = Ah + (size_t)(m0 + am) * Dd + ak;
    const unsigned short* AlG = Al + (size_t)(m0 + am) * Dd + ak;
    const float*          WG  = W + (size_t)(wkq * 16) * Dd + n0 + wn;

    f32x4 acc[4][4];
#pragma unroll
    for (int mt = 0; mt < 4; ++mt)
#pragma unroll
        for (int nt = 0; nt < 4; ++nt) acc[mt][nt] = (f32x4){0.f, 0.f, 0.f, 0.f};

    uint4 ar0, ar1, al0, al1;
    float wf[16];

    // preload k0 = 0
    ar0 = *(const uint4*)(AhG);     ar1 = *(const uint4*)(AhG + 8);
    al0 = *(const uint4*)(AlG);     al1 = *(const uint4*)(AlG + 8);
#pragma unroll
    for (int i = 0; i < 16; ++i) wf[i] = WG[(size_t)i * Dd];

#pragma unroll 1
    for (int k0 = 0; k0 < Dd; k0 += 32) {
        __syncthreads();    // previous iter's frag reads done
        *(uint4*)&Ash[am * 40 + ak]     = ar0;
        *(uint4*)&Ash[am * 40 + ak + 8] = ar1;
        *(uint4*)&Asl[am * 40 + ak]     = al0;
        *(uint4*)&Asl[am * 40 + ak + 8] = al1;
        {
            bf16x8 wh0, wh1, wl0, wl1;
#pragma unroll
            for (int i = 0; i < 8; ++i) {
                unsigned short h = bf16_rne(wf[i]);
                wh0[i] = (short)h;
                wl0[i] = (short)bf16_rne(wf[i] - bf16_to_f(h));
            }
#pragma unroll
            for (int i = 0; i < 8; ++i) {
                unsigned short h = bf16_rne(wf[8 + i]);
                wh1[i] = (short)h;
                wl1[i] = (short)bf16_rne(wf[8 + i] - bf16_to_f(h));
            }
            *(bf16x8*)&Wsh[wn * 40 + wkq * 16]     = wh0;
            *(bf16x8*)&Wsh[wn * 40 + wkq * 16 + 8] = wh1;
            *(bf16x8*)&Wsl[wn * 40 + wkq * 16]     = wl0;
            *(bf16x8*)&Wsl[wn * 40 + wkq * 16 + 8] = wl1;
        }
        __syncthreads();    // tile visible

        if (k0 + 32 < Dd) { // prefetch next tile (overlaps MFMA)
            const unsigned short* ah = AhG + k0 + 32;
            const unsigned short* al_ = AlG + k0 + 32;
            const float* wg = WG + (size_t)(k0 + 32) * Dd;
            ar0 = *(const uint4*)(ah);      ar1 = *(const uint4*)(ah + 8);
            al0 = *(const uint4*)(al_);     al1 = *(const uint4*)(al_ + 8);
#pragma unroll
            for (int i = 0; i < 16; ++i) wf[i] = wg[(size_t)i * Dd];
        }

        bf16x8 Afh[4], Afl[4], Wfh[4], Wfl[4];
#pragma unroll
        for (int mt = 0; mt < 4; ++mt) {
            Afh[mt] = *(bf16x8*)&Ash[(wr + mt * 16 + s) * 40 + q * 8];
            Afl[mt] = *(bf16x8*)&Asl[(wr + mt * 16 + s) * 40 + q * 8];
        }
#pragma unroll
        for (int nt = 0; nt < 4; ++nt) {
            Wfh[nt] = *(bf16x8*)&Wsh[(wc + nt * 16 + s) * 40 + q * 8];
            Wfl[nt] = *(bf16x8*)&Wsl[(wc + nt * 16 + s) * 40 + q * 8];
        }
#pragma unroll
        for (int mt = 0; mt < 4; ++mt)
#pragma unroll
            for (int nt = 0; nt < 4; ++nt) {
                f32x4 a = acc[mt][nt];
                a = MFMA16(Afl[mt], Wfh[nt], a);
                a = MFMA16(Afh[mt], Wfl[nt], a);
                a = MFMA16(Afh[mt], Wfh[nt], a);
                acc[mt][nt] = a;
            }
    }

    // epilogue: +bias, relu, store (C rows = q*4+r, cols = s within each 16x16 frag)
#pragma unroll
    for (int nt = 0; nt < 4; ++nt) {
        float bv = bias[n0 + wc + nt * 16 + s];
#pragma unroll
        for (int mt = 0; mt < 4; ++mt)
#pragma unroll
            for (int r = 0; r < 4; ++r) {
                int m = m0 + wr + mt * 16 + q * 4 + r;
                C[(size_t)m * Dd + n0 + wc + nt * 16 + s] = fmaxf(acc[mt][nt][r] + bv, 0.f);
            }
    }
}

// ---------------------------------------------------------------- gate: softmax(g @ gate_w + gb)
__global__ __launch_bounds__(256) void gate_kernel(const float* __restrict__ g,
                                                   const float* __restrict__ gw,
                                                   const float* __restrict__ gb,
                                                   float* __restrict__ wgt)
{
    int b = blockIdx.x;
    int tid = threadIdx.x;
    int lane = tid & 63;
    int wv = tid >> 6;

    float acc[16];
#pragma unroll
    for (int j = 0; j < 16; ++j) acc[j] = 0.f;

    const float* grow = g + (size_t)b * Dd;
#pragma unroll
    for (int it = 0; it < Dd / 256; ++it) {
        int d = tid + it * 256;
        float gv = grow[d];
        const float4* wr = (const float4*)(gw + (size_t)d * 16);
        float4 w0 = wr[0], w1 = wr[1], w2 = wr[2], w3 = wr[3];
        acc[0] += gv * w0.x;  acc[1] += gv * w0.y;  acc[2] += gv * w0.z;  acc[3] += gv * w0.w;
        acc[4] += gv * w1.x;  acc[5] += gv * w1.y;  acc[6] += gv * w1.z;  acc[7] += gv * w1.w;
        acc[8] += gv * w2.x;  acc[9] += gv * w2.y;  acc[10] += gv * w2.z; acc[11] += gv * w2.w;
        acc[12] += gv * w3.x; acc[13] += gv * w3.y; acc[14] += gv * w3.z; acc[15] += gv * w3.w;
    }

    __shared__ float red[64];
    __shared__ float logits[16];
#pragma unroll
    for (int j = 0; j < 16; ++j) {
        float v = acc[j];
#pragma unroll
        for (int m = 32; m >= 1; m >>= 1) v += __shfl_xor(v, m);
        if (lane == 0) red[wv * 16 + j] = v;
    }
    __syncthreads();
    if (tid < 16) {
        logits[tid] = gb[tid] + red[tid] + red[16 + tid] + red[32 + tid] + red[48 + tid];
    }
    __syncthreads();
    if (tid == 0) {
        float m = logits[0];
#pragma unroll
        for (int j = 1; j < 16; ++j) m = fmaxf(m, logits[j]);
        float ex[16], ssum = 0.f;
#pragma unroll
        for (int j = 0; j < 16; ++j) { ex[j] = __expf(logits[j] - m); ssum += ex[j]; }
        float inv = 1.f / ssum;
#pragma unroll
        for (int j = 0; j < 16; ++j) wgt[(size_t)b * 16 + j] = ex[j] * inv;
    }
}

// ---------------------------------------------------------------- MFMA split-bf16 2-layer LSTM
// grid = 1024 blocks of 64 threads (1 wave): block = (expert, 16-row batch chunk).
// BatchNorm folded into the x staging. Weights in VGPRs as MFMA B-frags (hi/lo).
__global__ __launch_bounds__(64, 1) void lstm_kernel(
    const float* __restrict__ x,
    const float* __restrict__ gamma, const float* __restrict__ beta,
    const float* __restrict__ mean,  const float* __restrict__ var,
    const float* __restrict__ pw,
    const float* __restrict__ dw, const float* __restrict__ db,
    float* __restrict__ eo)
{
    const int e  = blockIdx.x >> 6;
    const int b0 = (blockIdx.x & 63) * 16;
    const int l  = threadIdx.x;
    const int q  = l >> 4;     // quad
    const int s  = l & 15;

    __shared__ short xh[16 * 40], xlo[16 * 40];
    __shared__ short h1h[16 * 40], h1l[16 * 40];
    __shared__ short h2h[16 * 40], h2l[16 * 40];
    __shared__ float z1buf[16 * 84 + 4];
    __shared__ float z2buf[16 * 84 + 4];

    for (int i = l; i < 16 * 40; i += 64) {
        h1h[i] = 0; h1l[i] = 0; h2h[i] = 0; h2l[i] = 0;
    }

    const float* Wm = pw + (size_t)e * PWE;

    bf16x8 K1h[5], K1l[5], R1h[5], R1l[5], K2h[5], K2l[5], R2h[5], R2l[5];
#pragma unroll
    for (int n = 0; n < 5; ++n) {
#pragma unroll
        for (int j = 0; j < 8; ++j) {
            int k = q * 8 + j;
            int c = n * 16 + s;
            float w;
            unsigned short hi; float hf;
            w = Wm[k * 80 + c];
            hi = bf16_rne(w); hf = bf16_to_f(hi);
            K1h[n][j] = (short)hi; K1l[n][j] = (short)bf16_rne(w - hf);
            w = (k < Hh) ? Wm[2560 + k * 80 + c] : 0.f;
            hi = bf16_rne(w); hf = bf16_to_f(hi);
            R1h[n][j] = (short)hi; R1l[n][j] = (short)bf16_rne(w - hf);
            w = (k < Hh) ? Wm[4160 + k * 80 + c] : 0.f;
            hi = bf16_rne(w); hf = bf16_to_f(hi);
            K2h[n][j] = (short)hi; K2l[n][j] = (short)bf16_rne(w - hf);
            w = (k < Hh) ? Wm[5760 + k * 80 + c] : 0.f;
            hi = bf16_rne(w); hf = bf16_to_f(hi);
            R2h[n][j] = (short)hi; R2l[n][j] = (short)bf16_rne(w - hf);
        }
    }
    float bv1[5], bv2[5], dwr[5];
#pragma unroll
    for (int n = 0; n < 5; ++n) {
        bv1[n] = Wm[7360 + n * 16 + s];
        bv2[n] = Wm[7440 + n * 16 + s];
    }
#pragma unroll
    for (int i = 0; i < 5; ++i) dwr[i] = dw[e * Hh + 4 * i + q];

    float c1[5] = {0, 0, 0, 0, 0}, c2[5] = {0, 0, 0, 0, 0};
    float h2reg[5] = {0, 0, 0, 0, 0};

    const int row = l >> 2, fc = l & 3;           // x staging: lane covers 8 f of one row
    const float* xbase = x + ((size_t)(b0 + row) * Tt) * Ff + fc * 8;
    float scv[8], shv[8];
#pragma unroll
    for (int j = 0; j < 8; ++j) {
        int f = fc * 8 + j;
        float sc = gamma[f] * rsqrtf(var[f] + EPSc);
        scv[j] = sc;
        shv[j] = beta[f] - mean[f] * sc;
    }

#pragma unroll 1
    for (int t = 0; t < Tt; ++t) {
        // ---- stage x_t (BN applied) as bf16 hi/lo A-frags
        {
            float4 xa = *(const float4*)(xbase + (size_t)t * Ff);
            float4 xb = *(const float4*)(xbase + (size_t)t * Ff + 4);
            float xv[8] = {xa.x, xa.y, xa.z, xa.w, xb.x, xb.y, xb.z, xb.w};
            bf16x8 hv, lv;
#pragma unroll
            for (int j = 0; j < 8; ++j) {
                float xn_ = xv[j] * scv[j] + shv[j];
                unsigned short hi = bf16_rne(xn_);
                hv[j] = (short)hi;
                lv[j] = (short)bf16_rne(xn_ - bf16_to_f(hi));
            }
            *(bf16x8*)&xh[row * 40 + fc * 8]  = hv;
            *(bf16x8*)&xlo[row * 40 + fc * 8] = lv;
        }
        bf16x8 Xh  = *(bf16x8*)&xh[s * 40 + q * 8];
        bf16x8 Xl  = *(bf16x8*)&xlo[s * 40 + q * 8];
        bf16x8 H1a = *(bf16x8*)&h1h[s * 40 + q * 8];
        bf16x8 H1b = *(bf16x8*)&h1l[s * 40 + q * 8];
        bf16x8 H2a = *(bf16x8*)&h2h[s * 40 + q * 8];
        bf16x8 H2b = *(bf16x8*)&h2l[s * 40 + q * 8];

        f32x4 a1[5];
#pragma unroll
        for (int n = 0; n < 5; ++n) {
            f32x4 acc = {bv1[n], bv1[n], bv1[n], bv1[n]};
            acc = MFMA16(Xh,  K1h[n], acc);
            acc = MFMA16(Xh,  K1l[n], acc);
            acc = MFMA16(Xl,  K1h[n], acc);
            acc = MFMA16(H1a, R1h[n], acc);
            acc = MFMA16(H1a, R1l[n], acc);
            acc = MFMA16(H1b, R1h[n], acc);
            a1[n] = acc;
        }
#pragma unroll
        for (int n = 0; n < 5; ++n)
#pragma unroll
            for (int r = 0; r < 4; ++r)
                z1buf[(4 * q + r) * 84 + n * 16 + s] = a1[n][r];

#pragma unroll
        for (int i = 0; i < 5; ++i) {
            int u = 4 * i + q;
            f32x4 zz = *(f32x4*)&z1buf[s * 84 + 4 * u];
            float iv = sigmoidf_(zz[0]);
            float fv = sigmoidf_(zz[1]);
            float gv = fmaxf(zz[2], 0.f);
            float ov = sigmoidf_(zz[3]);
            c1[i] = fv * c1[i] + iv * gv;
            float h = ov * fmaxf(c1[i], 0.f);
            unsigned short hi = bf16_rne(h);
            h1h[s * 40 + u] = (short)hi;
            h1l[s * 40 + u] = (short)bf16_rne(h - bf16_to_f(hi));
        }

        bf16x8 H1c = *(bf16x8*)&h1h[s * 40 + q * 8];
        bf16x8 H1d = *(bf16x8*)&h1l[s * 40 + q * 8];
        f32x4 a2[5];
#pragma unroll
        for (int n = 0; n < 5; ++n) {
            f32x4 acc = {bv2[n], bv2[n], bv2[n], bv2[n]};
            acc = MFMA16(H1c, K2h[n], acc);
            acc = MFMA16(H1c, K2l[n], acc);
            acc = MFMA16(H1d, K2h[n], acc);
            acc = MFMA16(H2a, R2h[n], acc);
            acc = MFMA16(H2a, R2l[n], acc);
            acc = MFMA16(H2b, R2h[n], acc);
            a2[n] = acc;
        }
#pragma unroll
        for (int n = 0; n < 5; ++n)
#pragma unroll
            for (int r = 0; r < 4; ++r)
                z2buf[(4 * q + r) * 84 + n * 16 + s] = a2[n][r];

#pragma unroll
        for (int i = 0; i < 5; ++i) {
            int u = 4 * i + q;
            f32x4 zz = *(f32x4*)&z2buf[s * 84 + 4 * u];
            float iv = sigmoidf_(zz[0]);
            float fv = sigmoidf_(zz[1]);
            float gv = fmaxf(zz[2], 0.f);
            float ov = sigmoidf_(zz[3]);
            c2[i] = fv * c2[i] + iv * gv;
            float h = ov * fmaxf(c2[i], 0.f);
            h2reg[i] = h;
            unsigned short hi = bf16_rne(h);
            h2h[s * 40 + u] = (short)hi;
            h2l[s * 40 + u] = (short)bf16_rne(h - bf16_to_f(hi));
        }
    }

    float p = 0.f;
#pragma unroll
    for (int i = 0; i < 5; ++i) p += h2reg[i] * dwr[i];
    p += __shfl_xor(p, 16);
    p += __shfl_xor(p, 32);
    if (q == 0) eo[(size_t)e * Bsz + b0 + s] = db[e] + p;
}

// ---------------------------------------------------------------- combine
__global__ void combine_kernel(const float* __restrict__ wgt,
                               const float* __restrict__ eo,
                               float* __restrict__ out)
{
    int b = blockIdx.x * blockDim.x + threadIdx.x;
    if (b < Bsz) {
        float s = 0.f;
#pragma unroll
        for (int e = 0; e < Ee; ++e) s += wgt[(size_t)b * 16 + e] * eo[(size_t)e * Bsz + b];
        out[b] = s;
    }
}

// ----------------------------------------------------------------
extern "C" void kernel_launch(void* const* d_in, const int* in_sizes, int n_in,
                              void* d_out, int out_size, void* d_ws, size_t ws_size,
                              hipStream_t stream)
{
    const float* x     = (const float*)d_in[0];
    const float* gamma = (const float*)d_in[1];
    const float* beta  = (const float*)d_in[2];
    const float* mean  = (const float*)d_in[3];
    const float* var   = (const float*)d_in[4];
    const float* k1    = (const float*)d_in[5];
    const float* r1    = (const float*)d_in[6];
    const float* b1    = (const float*)d_in[7];
    const float* k2    = (const float*)d_in[8];
    const float* r2    = (const float*)d_in[9];
    const float* b2    = (const float*)d_in[10];
    const float* dw    = (const float*)d_in[11];
    const float* db    = (const float*)d_in[12];
    const float* fc1w  = (const float*)d_in[13];
    const float* fc1b  = (const float*)d_in[14];
    const float* gw    = (const float*)d_in[15];
    const float* gb    = (const float*)d_in[16];
    float* out = (float*)d_out;

    // workspace (34.17 MB, same footprint as round 3/4):
    float* g = (float*)d_ws;                                  // 4,194,304 f (16 MB)
    unsigned short* Ah = (unsigned short*)(g + (size_t)Bsz * Dd);   // 4,194,304 us (8 MB)
    unsigned short* Al = Ah + (size_t)Bsz * Dd;               // 8 MB
    float* pw  = (float*)(Al + (size_t)Bsz * Dd);             // 120,320 f
    float* wgt = pw + (size_t)Ee * PWE;                       // 16,384 f
    float* eo  = wgt + (size_t)Bsz * Ee;                      // 16,384 f

    aconv_kernel<<<(Bsz * Dd / 4 + 255) / 256, 256, 0, stream>>>(x, Ah, Al, Bsz * Dd / 4);
    repack2_kernel<<<(Ee * PWE + 255) / 256, 256, 0, stream>>>(k1, r1, b1, k2, r2, b2, pw);
    lstm_kernel<<<1024, 64, 0, stream>>>(x, gamma, beta, mean, var, pw, dw, db, eo);
    fc1_mfma<<<dim3(Dd / 128, Bsz / 128), 256, 0, stream>>>(Ah, Al, fc1w, fc1b, g);
    gate_kernel<<<Bsz, 256, 0, stream>>>(g, gw, gb, wgt);
    combine_kernel<<<4, 256, 0, stream>>>(wgt, eo, out);
}

// Round 6
// 600.282 us; speedup vs baseline: 3.5281x; 1.1210x over previous
//
#include <hip/hip_runtime.h>
#include <math.h>

#define Bsz 1024
#define Tt  128
#define Ff  32
#define Ee  16
#define Hh  20
#define Dd  4096
#define EPSc 1e-3f

// repacked fp32 weights per expert, gate-interleaved cols c = 4*u + g (g: i,f,g,o):
// K1p[32][80]@0, R1p[20][80]@2560, K2p[20][80]@4160, R2p[20][80]@5760,
// b1p[80]@7360, b2p[80]@7440  -> 7520 floats per expert
#define PWE 7520

typedef __attribute__((ext_vector_type(8))) short bf16x8;
typedef __attribute__((ext_vector_type(4))) float f32x4;

#define MFMA16(a,b,c) __builtin_amdgcn_mfma_f32_16x16x32_bf16(a, b, c, 0, 0, 0)

__device__ __forceinline__ float sigmoidf_(float x) {
    return 1.0f / (1.0f + __expf(-x));
}
__device__ __forceinline__ unsigned short bf16_rne(float f) {
    unsigned u = __float_as_uint(f);
    u += 0x7FFFu + ((u >> 16) & 1u);
    return (unsigned short)(u >> 16);
}
__device__ __forceinline__ float bf16_to_f(unsigned short h) {
    return __uint_as_float(((unsigned)h) << 16);
}

// ---------------------------------------------------------------- x prepass: BN + bf16 hi/lo split
// into per-(chunk,t,lane) A-fragment layout: elem (c,t,l)*8  holds xn[c*16+s][t][q*8..+8]
__global__ void xpack_kernel(const float* __restrict__ x,
                             const float* __restrict__ gamma, const float* __restrict__ beta,
                             const float* __restrict__ mean,  const float* __restrict__ var,
                             unsigned short* __restrict__ xph, unsigned short* __restrict__ xpl)
{
    __shared__ float sc[Ff], sh[Ff];
    int tid = threadIdx.x;
    if (tid < Ff) {
        float s = gamma[tid] * rsqrtf(var[tid] + EPSc);
        sc[tid] = s;
        sh[tid] = beta[tid] - mean[tid] * s;
    }
    __syncthreads();
    int idx = blockIdx.x * 256 + tid;           // 0 .. 64*128*64-1
    int c   = idx >> 13;
    int rem = idx & 8191;
    int t   = rem >> 6;
    int l   = rem & 63;
    int q   = l >> 4, s = l & 15;
    const float* xr = x + ((size_t)(c * 16 + s) * Tt + t) * Ff + q * 8;
    float4 v0 = *(const float4*)xr;
    float4 v1 = *(const float4*)(xr + 4);
    float xv[8] = {v0.x, v0.y, v0.z, v0.w, v1.x, v1.y, v1.z, v1.w};
    bf16x8 hv, lv;
#pragma unroll
    for (int j = 0; j < 8; ++j) {
        int f = q * 8 + j;
        float xn_ = xv[j] * sc[f] + sh[f];
        unsigned short hi = bf16_rne(xn_);
        hv[j] = (short)hi;
        lv[j] = (short)bf16_rne(xn_ - bf16_to_f(hi));
    }
    *(bf16x8*)(xph + (size_t)idx * 8) = hv;
    *(bf16x8*)(xpl + (size_t)idx * 8) = lv;
}

// ---------------------------------------------------------------- weight repack (gate-interleave)
__global__ void repack2_kernel(const float* __restrict__ k1, const float* __restrict__ r1,
                               const float* __restrict__ b1, const float* __restrict__ k2,
                               const float* __restrict__ r2, const float* __restrict__ b2,
                               float* __restrict__ pw)
{
    int idx = blockIdx.x * blockDim.x + threadIdx.x;
    if (idx >= Ee * PWE) return;
    int e = idx / PWE;
    int o = idx % PWE;
    float v;
    if (o < 7360) {
        int c = o % 80, u = c >> 2, g = c & 3;
        int co = g * 20 + u;
        if (o < 2560) {
            int kk = o / 80;
            v = k1[((size_t)e * Ff + kk) * 80 + co];
        } else if (o < 4160) {
            int kk = (o - 2560) / 80;
            v = r1[((size_t)e * Hh + kk) * 80 + co];
        } else if (o < 5760) {
            int kk = (o - 4160) / 80;
            v = k2[((size_t)e * Hh + kk) * 80 + co];
        } else {
            int kk = (o - 5760) / 80;
            v = r2[((size_t)e * Hh + kk) * 80 + co];
        }
    } else if (o < 7440) {
        int c = o - 7360, u = c >> 2, g = c & 3;
        v = b1[(size_t)e * 80 + g * 20 + u];
    } else {
        int c = o - 7440, u = c >> 2, g = c & 3;
        v = b2[(size_t)e * 80 + g * 20 + u];
    }
    pw[idx] = v;
}

// ---------------------------------------------------------------- fused lstm + fc1
// 512 blocks x 256 thr, 2 blocks/CU -> 2 waves/SIMD. Even blocks: 4 independent
// single-wave LSTM tiles (latency-bound). Odd blocks: one 128x128 fc1 MFMA tile
// (pipe-bound). fc1 hides in lstm's stall cycles (m114 co-scheduling).
#define TILE_LDS 10752
__global__ __launch_bounds__(256, 2) void fused_kernel(
    const unsigned short* __restrict__ xph, const unsigned short* __restrict__ xpl,
    const float* __restrict__ pw, const float* __restrict__ dw, const float* __restrict__ db,
    float* __restrict__ eo,
    const float* __restrict__ x, const float* __restrict__ W,
    const float* __restrict__ bias, float* __restrict__ C)
{
    __shared__ __align__(16) char smem[43008];

    if ((blockIdx.x & 1) == 0) {
        // ================= LSTM path: wave w handles tile (blockIdx>>1)*4+w =================
        const int w = threadIdx.x >> 6;
        const int l = threadIdx.x & 63;
        const int q = l >> 4, s = l & 15;
        const int tile = ((blockIdx.x >> 1) << 2) + w;
        const int e = tile >> 6;
        const int c = tile & 63;
        const int b0 = c * 16;

        char* base = smem + w * TILE_LDS;
        short* h1h = (short*)base;          // 640 shorts each
        short* h1l = h1h + 640;
        short* h2h = h1l + 640;
        short* h2l = h2h + 640;
        float* zb  = (float*)(base + 5120); // 16*84 floats (shared by both layers)

        {   // zero h state
            int* hz = (int*)base;
            for (int i = l; i < 1280; i += 64) hz[i] = 0;
        }

        const float* Wm = pw + (size_t)e * PWE;
        bf16x8 K1h[5], K1l[5], R1h[5], R1l[5], K2h[5], K2l[5], R2h[5], R2l[5];
#pragma unroll
        for (int n = 0; n < 5; ++n) {
#pragma unroll
            for (int j = 0; j < 8; ++j) {
                int k = q * 8 + j;
                int cc = n * 16 + s;
                float wv_;
                unsigned short hi; float hf;
                wv_ = Wm[k * 80 + cc];
                hi = bf16_rne(wv_); hf = bf16_to_f(hi);
                K1h[n][j] = (short)hi; K1l[n][j] = (short)bf16_rne(wv_ - hf);
                wv_ = (k < Hh) ? Wm[2560 + k * 80 + cc] : 0.f;
                hi = bf16_rne(wv_); hf = bf16_to_f(hi);
                R1h[n][j] = (short)hi; R1l[n][j] = (short)bf16_rne(wv_ - hf);
                wv_ = (k < Hh) ? Wm[4160 + k * 80 + cc] : 0.f;
                hi = bf16_rne(wv_); hf = bf16_to_f(hi);
                K2h[n][j] = (short)hi; K2l[n][j] = (short)bf16_rne(wv_ - hf);
                wv_ = (k < Hh) ? Wm[5760 + k * 80 + cc] : 0.f;
                hi = bf16_rne(wv_); hf = bf16_to_f(hi);
                R2h[n][j] = (short)hi; R2l[n][j] = (short)bf16_rne(wv_ - hf);
            }
        }
        float bv1[5], bv2[5], dwr[5];
#pragma unroll
        for (int n = 0; n < 5; ++n) {
            bv1[n] = Wm[7360 + n * 16 + s];
            bv2[n] = Wm[7440 + n * 16 + s];
        }
#pragma unroll
        for (int i = 0; i < 5; ++i) dwr[i] = dw[e * Hh + 4 * i + q];

        float c1[5] = {0, 0, 0, 0, 0}, c2[5] = {0, 0, 0, 0, 0};
        float h2reg[5] = {0, 0, 0, 0, 0};

        const unsigned short* xbh = xph + (size_t)c * 65536 + l * 8;
        const unsigned short* xbl = xpl + (size_t)c * 65536 + l * 8;
        bf16x8 xch = *(const bf16x8*)xbh;
        bf16x8 xcl = *(const bf16x8*)xbl;

#pragma unroll 1
        for (int t = 0; t < Tt; ++t) {
            bf16x8 xnh = xch, xnl = xcl;
            if (t < Tt - 1) {       // prefetch t+1 (overlaps this step's compute)
                xnh = *(const bf16x8*)(xbh + (t + 1) * 512);
                xnl = *(const bf16x8*)(xbl + (t + 1) * 512);
            }
            bf16x8 H1a = *(bf16x8*)&h1h[s * 40 + q * 8];
            bf16x8 H1b = *(bf16x8*)&h1l[s * 40 + q * 8];
            bf16x8 H2a = *(bf16x8*)&h2h[s * 40 + q * 8];
            bf16x8 H2b = *(bf16x8*)&h2l[s * 40 + q * 8];

            f32x4 a1[5];
#pragma unroll
            for (int n = 0; n < 5; ++n) {
                f32x4 acc = {bv1[n], bv1[n], bv1[n], bv1[n]};
                acc = MFMA16(xch, K1h[n], acc);
                acc = MFMA16(xch, K1l[n], acc);
                acc = MFMA16(xcl, K1h[n], acc);
                acc = MFMA16(H1a, R1h[n], acc);
                acc = MFMA16(H1a, R1l[n], acc);
                acc = MFMA16(H1b, R1h[n], acc);
                a1[n] = acc;
            }
#pragma unroll
            for (int n = 0; n < 5; ++n)
#pragma unroll
                for (int r = 0; r < 4; ++r)
                    zb[(4 * q + r) * 84 + n * 16 + s] = a1[n][r];

#pragma unroll
            for (int i = 0; i < 5; ++i) {
                int u = 4 * i + q;
                f32x4 zz = *(f32x4*)&zb[s * 84 + 4 * u];
                float iv = sigmoidf_(zz[0]);
                float fv = sigmoidf_(zz[1]);
                float gv = fmaxf(zz[2], 0.f);
                float ov = sigmoidf_(zz[3]);
                c1[i] = fv * c1[i] + iv * gv;
                float h = ov * fmaxf(c1[i], 0.f);
                unsigned short hi = bf16_rne(h);
                h1h[s * 40 + u] = (short)hi;
                h1l[s * 40 + u] = (short)bf16_rne(h - bf16_to_f(hi));
            }

            bf16x8 H1c = *(bf16x8*)&h1h[s * 40 + q * 8];
            bf16x8 H1d = *(bf16x8*)&h1l[s * 40 + q * 8];
            f32x4 a2[5];
#pragma unroll
            for (int n = 0; n < 5; ++n) {
                f32x4 acc = {bv2[n], bv2[n], bv2[n], bv2[n]};
                acc = MFMA16(H1c, K2h[n], acc);
                acc = MFMA16(H1c, K2l[n], acc);
                acc = MFMA16(H1d, K2h[n], acc);
                acc = MFMA16(H2a, R2h[n], acc);
                acc = MFMA16(H2a, R2l[n], acc);
                acc = MFMA16(H2b, R2h[n], acc);
                a2[n] = acc;
            }
#pragma unroll
            for (int n = 0; n < 5; ++n)
#pragma unroll
                for (int r = 0; r < 4; ++r)
                    zb[(4 * q + r) * 84 + n * 16 + s] = a2[n][r];

#pragma unroll
            for (int i = 0; i < 5; ++i) {
                int u = 4 * i + q;
                f32x4 zz = *(f32x4*)&zb[s * 84 + 4 * u];
                float iv = sigmoidf_(zz[0]);
                float fv = sigmoidf_(zz[1]);
                float gv = fmaxf(zz[2], 0.f);
                float ov = sigmoidf_(zz[3]);
                c2[i] = fv * c2[i] + iv * gv;
                float h = ov * fmaxf(c2[i], 0.f);
                h2reg[i] = h;
                unsigned short hi = bf16_rne(h);
                h2h[s * 40 + u] = (short)hi;
                h2l[s * 40 + u] = (short)bf16_rne(h - bf16_to_f(hi));
            }
            xch = xnh; xcl = xnl;
        }

        float p = 0.f;
#pragma unroll
        for (int i = 0; i < 5; ++i) p += h2reg[i] * dwr[i];
        p += __shfl_xor(p, 16);
        p += __shfl_xor(p, 32);
        if (q == 0) eo[(size_t)e * Bsz + b0 + s] = db[e] + p;

    } else {
        // ================= fc1 path: 128x128 split-bf16 MFMA tile =================
        unsigned short* Ash = (unsigned short*)smem;      // 128*40 each
        unsigned short* Asl = Ash + 5120;
        unsigned short* Wsh = Asl + 5120;
        unsigned short* Wsl = Wsh + 5120;

        const int tid = threadIdx.x;
        const int wv = tid >> 6, l = tid & 63, q = l >> 4, s = l & 15;
        const int id = blockIdx.x >> 1;
        const int n0 = (id & 31) * 128, m0 = (id >> 5) * 128;
        const int wr = (wv & 1) * 64, wc = (wv >> 1) * 64;

        const int am = tid >> 1, ak = (tid & 1) * 16;
        const int wn = tid & 127, wkq = tid >> 7;

        const float* AG = x + (size_t)(m0 + am) * Dd + ak;
        const float* WG = W + (size_t)(wkq * 16) * Dd + n0 + wn;

        f32x4 acc[4][4];
#pragma unroll
        for (int mt = 0; mt < 4; ++mt)
#pragma unroll
            for (int nt = 0; nt < 4; ++nt) acc[mt][nt] = (f32x4){0.f, 0.f, 0.f, 0.f};

        float af[16], wf[16];
#pragma unroll
        for (int i = 0; i < 4; ++i) *(float4*)&af[i * 4] = *(const float4*)(AG + i * 4);
#pragma unroll
        for (int i = 0; i < 16; ++i) wf[i] = WG[(size_t)i * Dd];

#pragma unroll 1
        for (int k0 = 0; k0 < Dd; k0 += 32) {
            __syncthreads();
            {
                bf16x8 h0, h1, l0, l1;
#pragma unroll
                for (int i = 0; i < 8; ++i) {
                    unsigned short h = bf16_rne(af[i]);
                    h0[i] = (short)h; l0[i] = (short)bf16_rne(af[i] - bf16_to_f(h));
                }
#pragma unroll
                for (int i = 0; i < 8; ++i) {
                    unsigned short h = bf16_rne(af[8 + i]);
                    h1[i] = (short)h; l1[i] = (short)bf16_rne(af[8 + i] - bf16_to_f(h));
                }
                *(bf16x8*)&Ash[am * 40 + ak]     = h0;
                *(bf16x8*)&Ash[am * 40 + ak + 8] = h1;
                *(bf16x8*)&Asl[am * 40 + ak]     = l0;
                *(bf16x8*)&Asl[am * 40 + ak + 8] = l1;
            }
            {
                bf16x8 h0, h1, l0, l1;
#pragma unroll
                for (int i = 0; i < 8; ++i) {
                    unsigned short h = bf16_rne(wf[i]);
                    h0[i] = (short)h; l0[i] = (short)bf16_rne(wf[i] - bf16_to_f(h));
                }
#pragma unroll
                for (int i = 0; i < 8; ++i) {
                    unsigned short h = bf16_rne(wf[8 + i]);
                    h1[i] = (short)h; l1[i] = (short)bf16_rne(wf[8 + i] - bf16_to_f(h));
                }
                *(bf16x8*)&Wsh[wn * 40 + wkq * 16]     = h0;
                *(bf16x8*)&Wsh[wn * 40 + wkq * 16 + 8] = h1;
                *(bf16x8*)&Wsl[wn * 40 + wkq * 16]     = l0;
                *(bf16x8*)&Wsl[wn * 40 + wkq * 16 + 8] = l1;
            }
            __syncthreads();

            if (k0 + 32 < Dd) {
                const float* ag = AG + k0 + 32;
                const float* wg = WG + (size_t)(k0 + 32) * Dd;
#pragma unroll
                for (int i = 0; i < 4; ++i) *(float4*)&af[i * 4] = *(const float4*)(ag + i * 4);
#pragma unroll
                for (int i = 0; i < 16; ++i) wf[i] = wg[(size_t)i * Dd];
            }

            bf16x8 Afh[4], Afl[4], Wfh[4], Wfl[4];
#pragma unroll
            for (int mt = 0; mt < 4; ++mt) {
                Afh[mt] = *(bf16x8*)&Ash[(wr + mt * 16 + s) * 40 + q * 8];
                Afl[mt] = *(bf16x8*)&Asl[(wr + mt * 16 + s) * 40 + q * 8];
            }
#pragma unroll
            for (int nt = 0; nt < 4; ++nt) {
                Wfh[nt] = *(bf16x8*)&Wsh[(wc + nt * 16 + s) * 40 + q * 8];
                Wfl[nt] = *(bf16x8*)&Wsl[(wc + nt * 16 + s) * 40 + q * 8];
            }
#pragma unroll
            for (int mt = 0; mt < 4; ++mt)
#pragma unroll
                for (int nt = 0; nt < 4; ++nt) {
                    f32x4 a = acc[mt][nt];
                    a = MFMA16(Afl[mt], Wfh[nt], a);
                    a = MFMA16(Afh[mt], Wfl[nt], a);
                    a = MFMA16(Afh[mt], Wfh[nt], a);
                    acc[mt][nt] = a;
                }
        }

#pragma unroll
        for (int nt = 0; nt < 4; ++nt) {
            float bv = bias[n0 + wc + nt * 16 + s];
#pragma unroll
            for (int mt = 0; mt < 4; ++mt)
#pragma unroll
                for (int r = 0; r < 4; ++r) {
                    int m = m0 + wr + mt * 16 + q * 4 + r;
                    C[(size_t)m * Dd + n0 + wc + nt * 16 + s] = fmaxf(acc[mt][nt][r] + bv, 0.f);
                }
        }
    }
}

// ---------------------------------------------------------------- gate: softmax(g @ gate_w + gb) + combine
__global__ __launch_bounds__(256) void gate_kernel(const float* __restrict__ g,
                                                   const float* __restrict__ gw,
                                                   const float* __restrict__ gb,
                                                   const float* __restrict__ eo,
                                                   float* __restrict__ out)
{
    int b = blockIdx.x;
    int tid = threadIdx.x;
    int lane = tid & 63;
    int wv = tid >> 6;

    float acc[16];
#pragma unroll
    for (int j = 0; j < 16; ++j) acc[j] = 0.f;

    const float* grow = g + (size_t)b * Dd;
#pragma unroll
    for (int it = 0; it < Dd / 256; ++it) {
        int d = tid + it * 256;
        float gv = grow[d];
        const float4* wr = (const float4*)(gw + (size_t)d * 16);
        float4 w0 = wr[0], w1 = wr[1], w2 = wr[2], w3 = wr[3];
        acc[0] += gv * w0.x;  acc[1] += gv * w0.y;  acc[2] += gv * w0.z;  acc[3] += gv * w0.w;
        acc[4] += gv * w1.x;  acc[5] += gv * w1.y;  acc[6] += gv * w1.z;  acc[7] += gv * w1.w;
        acc[8] += gv * w2.x;  acc[9] += gv * w2.y;  acc[10] += gv * w2.z; acc[11] += gv * w2.w;
        acc[12] += gv * w3.x; acc[13] += gv * w3.y; acc[14] += gv * w3.z; acc[15] += gv * w3.w;
    }

    __shared__ float red[64];
    __shared__ float logits[16];
#pragma unroll
    for (int j = 0; j < 16; ++j) {
        float v = acc[j];
#pragma unroll
        for (int m = 32; m >= 1; m >>= 1) v += __shfl_xor(v, m);
        if (lane == 0) red[wv * 16 + j] = v;
    }
    __syncthreads();
    if (tid < 16) {
        logits[tid] = gb[tid] + red[tid] + red[16 + tid] + red[32 + tid] + red[48 + tid];
    }
    __syncthreads();
    if (tid == 0) {
        float m = logits[0];
#pragma unroll
        for (int j = 1; j < 16; ++j) m = fmaxf(m, logits[j]);
        float ex[16], ssum = 0.f;
#pragma unroll
        for (int j = 0; j < 16; ++j) { ex[j] = __expf(logits[j] - m); ssum += ex[j]; }
        float inv = 1.f / ssum;
        float o = 0.f;
#pragma unroll
        for (int j = 0; j < 16; ++j) o += ex[j] * inv * eo[(size_t)j * Bsz + b];
        out[b] = o;
    }
}

// ----------------------------------------------------------------
extern "C" void kernel_launch(void* const* d_in, const int* in_sizes, int n_in,
                              void* d_out, int out_size, void* d_ws, size_t ws_size,
                              hipStream_t stream)
{
    const float* x     = (const float*)d_in[0];
    const float* gamma = (const float*)d_in[1];
    const float* beta  = (const float*)d_in[2];
    const float* mean  = (const float*)d_in[3];
    const float* var   = (const float*)d_in[4];
    const float* k1    = (const float*)d_in[5];
    const float* r1    = (const float*)d_in[6];
    const float* b1    = (const float*)d_in[7];
    const float* k2    = (const float*)d_in[8];
    const float* r2    = (const float*)d_in[9];
    const float* b2    = (const float*)d_in[10];
    const float* dw    = (const float*)d_in[11];
    const float* db    = (const float*)d_in[12];
    const float* fc1w  = (const float*)d_in[13];
    const float* fc1b  = (const float*)d_in[14];
    const float* gw    = (const float*)d_in[15];
    const float* gb    = (const float*)d_in[16];
    float* out = (float*)d_out;

    // workspace: 33.1 MB (<= previously-proven 34.2 MB footprint)
    float* g = (float*)d_ws;                                        // 4,194,304 f (16 MB)
    unsigned short* xph = (unsigned short*)(g + (size_t)Bsz * Dd);  // 4,194,304 us (8 MB)
    unsigned short* xpl = xph + (size_t)Bsz * Dd / 2 * 2;           // 8 MB (same count)
    float* pw  = (float*)(xpl + (size_t)4194304);                   // 120,320 f
    float* eo  = pw + (size_t)Ee * PWE;                             // 16,384 f

    xpack_kernel<<<2048, 256, 0, stream>>>(x, gamma, beta, mean, var, xph, xpl);
    repack2_kernel<<<(Ee * PWE + 255) / 256, 256, 0, stream>>>(k1, r1, b1, k2, r2, b2, pw);
    fused_kernel<<<512, 256, 0, stream>>>(xph, xpl, pw, dw, db, eo, x, fc1w, fc1b, g);
    gate_kernel<<<Bsz, 256, 0, stream>>>(g, gw, gb, eo, out);
}